// Round 9
// baseline (780.766 us; speedup 1.0000x reference)
//
#include <hip/hip_runtime.h>
#include <hip/hip_bf16.h>

#define NB 8
#define NM 20000
#define NR 50000
#define NE 100000
#define BN_EPS 1e-5f

typedef unsigned int u32;

using short8 = __attribute__((ext_vector_type(8))) short;  // 8 bf16
using f32x4 = __attribute__((ext_vector_type(4))) float;

#define MFMA16(a, b, c) __builtin_amdgcn_mfma_f32_16x16x32_bf16(a, b, c, 0, 0, 0)

__device__ inline u32 f2bf_bits(float f) {
    u32 x = __float_as_uint(f);
    return (x + 0x7fffu + ((x >> 16) & 1u)) >> 16;
}
__device__ inline void storev(float* p, float v) { *p = v; }
__device__ inline void storev(__hip_bfloat16* p, float v) {
    *(unsigned short*)p = (unsigned short)f2bf_bits(v);
}

// accumulate 16 bf16 cols (32B) into fp32
__device__ inline void acc16(const __hip_bfloat16* p, float* g) {
    uint4 q0 = *(const uint4*)p;
    uint4 q1 = *(const uint4*)(p + 8);
    u32 ww[8] = {q0.x, q0.y, q0.z, q0.w, q1.x, q1.y, q1.z, q1.w};
#pragma unroll
    for (int q = 0; q < 8; ++q) {
        g[q * 2] += __uint_as_float(ww[q] << 16);
        g[q * 2 + 1] += __uint_as_float(ww[q] & 0xFFFF0000u);
    }
}

// ---------------------------------------------------------------------------
// CSR build (fused 4-list histogram / fill)
// ---------------------------------------------------------------------------
__global__ __launch_bounds__(256) void hist4_k(const int* __restrict__ l0,
                                               const int* __restrict__ l1,
                                               const int* __restrict__ l2,
                                               const int* __restrict__ l3,
                                               int* c0, int* c1, int* c2, int* c3) {
    int i = blockIdx.x * 256 + threadIdx.x;
    if (i >= NE) return;
    const int* e;
    int* c;
    switch (blockIdx.y) {
        case 0: e = l0; c = c0; break;
        case 1: e = l1; c = c1; break;
        case 2: e = l2; c = c2; break;
        default: e = l3; c = c3; break;
    }
    atomicAdd(&c[e[NE + i]], 1);
}

__global__ __launch_bounds__(256) void fill4_k(
    const int* __restrict__ l0, const int* __restrict__ l1,
    const int* __restrict__ l2, const int* __restrict__ l3,
    const int* __restrict__ o0, const int* __restrict__ o1,
    const int* __restrict__ o2, const int* __restrict__ o3,
    int* u0, int* u1, int* u2, int* u3,
    int* x0, int* x1, int* x2, int* x3) {
    int i = blockIdx.x * 256 + threadIdx.x;
    if (i >= NE) return;
    const int *e, *o;
    int *cur, *idx;
    switch (blockIdx.y) {
        case 0: e = l0; o = o0; cur = u0; idx = x0; break;
        case 1: e = l1; o = o1; cur = u1; idx = x1; break;
        case 2: e = l2; o = o2; cur = u2; idx = x2; break;
        default: e = l3; o = o3; cur = u3; idx = x3; break;
    }
    int d = e[NE + i];
    int p = atomicAdd(&cur[d], 1);
    idx[o[d] + p] = e[i];
}

__global__ __launch_bounds__(1024) void scan4_k(
    const int* c0, int* o0, int n0, const int* c1, int* o1, int n1,
    const int* c2, int* o2, int n2, const int* c3, int* o3, int n3) {
    const int* c; int* o; int n;
    if (blockIdx.x == 0) { c = c0; o = o0; n = n0; }
    else if (blockIdx.x == 1) { c = c1; o = o1; n = n1; }
    else if (blockIdx.x == 2) { c = c2; o = o2; n = n2; }
    else { c = c3; o = o3; n = n3; }
    __shared__ int wsum[16];
    __shared__ int carry_s;
    int t = threadIdx.x, lane = t & 63, w = t >> 6;
    if (t == 0) carry_s = 0;
    __syncthreads();
    for (int base = 0; base < n; base += 1024) {
        int i = base + t;
        int x = (i < n) ? c[i] : 0;
#pragma unroll
        for (int s = 1; s < 64; s <<= 1) {
            int y = __shfl_up(x, s);
            if (lane >= s) x += y;
        }
        if (lane == 63) wsum[w] = x;
        __syncthreads();
        if (w == 0) {
            int ws = (lane < 16) ? wsum[lane] : 0;
#pragma unroll
            for (int s = 1; s < 16; s <<= 1) {
                int y = __shfl_up(ws, s);
                if (lane >= s) ws += y;
            }
            if (lane < 16) wsum[lane] = ws;
        }
        __syncthreads();
        int wbase = (w > 0) ? wsum[w - 1] : 0;
        int incl = x + wbase + carry_s;
        if (i < n) o[i + 1] = incl;
        __syncthreads();
        if (t == 1023) carry_s = incl;
        __syncthreads();
    }
    if (t == 0) o[0] = 0;
}

// ---------------------------------------------------------------------------
// degree-sort: deg[i] = d1+d2 (clamp 63) + histogram; then counting scatter
// ---------------------------------------------------------------------------
__global__ __launch_bounds__(256) void deghist_k(
    const int* __restrict__ o1a, const int* __restrict__ o2a, int na,
    int* __restrict__ dega, int* __restrict__ hista,
    const int* __restrict__ o1b, const int* __restrict__ o2b, int nb,
    int* __restrict__ degb, int* __restrict__ histb) {
    int list = blockIdx.y;
    const int* o1 = list ? o1b : o1a;
    const int* o2 = list ? o2b : o2a;
    int n = list ? nb : na;
    int* deg = list ? degb : dega;
    int* hist = list ? histb : hista;
    int i = blockIdx.x * 256 + threadIdx.x;
    if (i < n) {
        int d = (o1[i + 1] - o1[i]) + (o2[i + 1] - o2[i]);
        d = min(d, 63);
        deg[i] = d;
        atomicAdd(&hist[d], 1);
    }
}

__global__ __launch_bounds__(256) void permscatter_k(
    const int* __restrict__ dega, const int* __restrict__ hista,
    int* __restrict__ cura, int* __restrict__ perma, int na,
    const int* __restrict__ degb, const int* __restrict__ histb,
    int* __restrict__ curb, int* __restrict__ permb, int nb) {
    int list = blockIdx.y;
    const int* deg = list ? degb : dega;
    const int* hist = list ? histb : hista;
    int* cur = list ? curb : cura;
    int* perm = list ? permb : perma;
    int n = list ? nb : na;
    __shared__ int base[64];
    int t = threadIdx.x;
    if (t < 64) {  // wave 0: exclusive scan of 64-entry histogram
        int v = hist[t];
        int x = v;
#pragma unroll
        for (int s = 1; s < 64; s <<= 1) {
            int y = __shfl_up(x, s);
            if (t >= s) x += y;
        }
        base[t] = x - v;
    }
    __syncthreads();
    int i = blockIdx.x * 256 + t;
    if (i < n) {
        int d = deg[i];
        int p = base[d] + atomicAdd(&cur[d], 1);
        perm[p] = i;
    }
}

// ---------------------------------------------------------------------------
// prep_all: grid-fused admin.
//  blk <  NCAST              : nodes [B,M,128] f32 -> node-major bf16 [M,B,128]
//  blk in [NCAST, +128)      : WtB1 frags + bias1 (2 k per block)
//  blk in [NCAST+128, +256)  : Wq_x = (w_ma1@w_r2x)@w_ra2 ; c1_x (per row h)
// ---------------------------------------------------------------------------
#define NCAST 10000
__global__ __launch_bounds__(256) void prep_all_k(
    const float* __restrict__ nodes, __hip_bfloat16* __restrict__ nb16,
    const float* __restrict__ w_rct, const float* __restrict__ w_prd,
    const float* __restrict__ w_ra1, const float* __restrict__ b_rct,
    const float* __restrict__ b_prd, const float* __restrict__ b_ra1,
    short* __restrict__ WtB1, float* __restrict__ bias1,
    const float* __restrict__ w_ma1, const float* __restrict__ w_r2rct,
    const float* __restrict__ w_r2prd, const float* __restrict__ b_r2rct,
    const float* __restrict__ b_r2prd, const float* __restrict__ w_ra2,
    const float* __restrict__ b_ra2, float* __restrict__ Wq_r,
    float* __restrict__ Wq_p, float* __restrict__ c1_r, float* __restrict__ c1_p) {
    __shared__ float smem[384];
    const int blk = blockIdx.x, t = threadIdx.x;
    if (blk < NCAST) {  // cast section
        int id = blk * 256 + t;
        int c8 = (id & 15) * 8;
        int b = (id >> 4) & 7;
        int m = id >> 7;
        const float* p = nodes + ((size_t)b * NM + m) * 128 + c8;
        float4 a = *(const float4*)p;
        float4 b2 = *(const float4*)(p + 4);
        u32 pk0 = f2bf_bits(a.x) | (f2bf_bits(a.y) << 16);
        u32 pk1 = f2bf_bits(a.z) | (f2bf_bits(a.w) << 16);
        u32 pk2 = f2bf_bits(b2.x) | (f2bf_bits(b2.y) << 16);
        u32 pk3 = f2bf_bits(b2.z) | (f2bf_bits(b2.w) << 16);
        *(uint4*)(nb16 + ((size_t)m * 8 + b) * 128 + c8) = make_uint4(pk0, pk1, pk2, pk3);
        return;
    }
    if (blk < NCAST + 128) {  // WtB1 frags: k = (blk-NCAST)*2 + (t>>7)
        float (*col2)[128] = (float(*)[128])smem;
        int half = t >> 7, h = t & 127;
        int k = (blk - NCAST) * 2 + half;
        const float* wsrc = (k < 128) ? w_rct : w_prd;
        int kk = k & 127;
        col2[half][h] = wsrc[h * 128 + kk];
        __syncthreads();
        float s = 0.f;
#pragma unroll 4
        for (int j = 0; j < 128; ++j) s = fmaf(w_ra1[h * 128 + j], col2[half][j], s);
        int ks = k >> 5, hi = (k >> 3) & 3, j2 = k & 7;
        int ntile = h >> 4, lc = h & 15, lane = hi * 16 + lc;
        WtB1[((ntile * 8 + ks) * 64 + lane) * 8 + j2] = (short)f2bf_bits(s);
        if (k == 0) {
            float sb1 = 0.f, sb2 = 0.f;
            for (int j = 0; j < 128; ++j) {
                float w = w_ra1[h * 128 + j];
                sb1 = fmaf(w, b_rct[j], sb1);
                sb2 = fmaf(w, b_prd[j], sb2);
            }
            bias1[h] = b_ra1[h];
            bias1[128 + h] = sb1;
            bias1[256 + h] = sb2;
        }
        return;
    }
    // Wq chain section: blk2 in [0,256): sec = blk2>=128, h = blk2&127
    float* rowv = smem;
    float* Prow = smem + 128;
    float* red = smem + 256;
    int blk2 = blk - (NCAST + 128);
    bool sec = blk2 >= 128;
    int h = blk2 & 127;
    const float* wr2 = sec ? w_r2prd : w_r2rct;
    const float* br2 = sec ? b_r2prd : b_r2rct;
    float* Wq = sec ? Wq_p : Wq_r;
    float* c1 = sec ? c1_p : c1_r;
    if (t < 128) rowv[t] = w_ma1[h * 128 + t];
    __syncthreads();
    if (t < 128) {
        float s = 0.f;
#pragma unroll 4
        for (int j = 0; j < 128; ++j) s = fmaf(rowv[j], wr2[j * 128 + t], s);
        Prow[t] = s;
        red[t] = rowv[t] * br2[t];
    }
    __syncthreads();
    for (int o = 64; o > 0; o >>= 1) {
        if (t < o) red[t] += red[t + o];
        __syncthreads();
    }
    float c1a = red[0];
    __syncthreads();
    if (t < 128) {
        float s = 0.f;
#pragma unroll 4
        for (int j = 0; j < 128; ++j) s = fmaf(Prow[j], w_ra2[j * 128 + t], s);
        Wq[h * 128 + t] = s;
        red[t] = Prow[t] * b_ra2[t];
    }
    __syncthreads();
    for (int o = 64; o > 0; o >>= 1) {
        if (t < o) red[t] += red[t + o];
        __syncthreads();
    }
    if (t == 0) c1[h] = red[0] + c1a;
}

// ---------------------------------------------------------------------------
// deterministic stat reduction: part[nblk][256] -> pp[64][256]
// ---------------------------------------------------------------------------
__global__ __launch_bounds__(256) void reduce_part_k(const float* __restrict__ part,
                                                     int nblk, int chunk,
                                                     float* __restrict__ pp) {
    int t = threadIdx.x, j = blockIdx.x;
    int r0 = j * chunk;
    int r1 = min(nblk, r0 + chunk);
    float s = 0.f;
    for (int r = r0; r < r1; ++r) s += part[(size_t)r * 256 + t];
    pp[j * 256 + t] = s;
}

// ---------------------------------------------------------------------------
// finalize1: from pp1 stats + precomputed Wq/c1, emit WtB2 frags + bias2.
// ---------------------------------------------------------------------------
__global__ __launch_bounds__(128) void finalize1_k(
    const float* __restrict__ pp, const float* __restrict__ Wq_r,
    const float* __restrict__ Wq_p, const float* __restrict__ c1_r,
    const float* __restrict__ c1_p, const float* __restrict__ b_ma1,
    const float* __restrict__ g, const float* __restrict__ beta, float Nf,
    short* __restrict__ WtB, float* __restrict__ bias) {
    int k = blockIdx.x, h = threadIdx.x, kk = k & 127;
    const float* Wq = (k < 128) ? Wq_r : Wq_p;
    float ssum = 0.f, ssq = 0.f;
#pragma unroll 8
    for (int j = 0; j < 64; ++j) {
        ssum += pp[j * 256 + kk];
        ssq += pp[j * 256 + 128 + kk];
    }
    float mean = ssum / Nf;
    float var = ssq / Nf - mean * mean;
    float sv = g[kk] * rsqrtf(var + BN_EPS);
    float v = Wq[h * 128 + kk] * sv;
    int ks = k >> 5, hi = (k >> 3) & 3, j2 = k & 7;
    int ntile = h >> 4, lc = h & 15, lane = hi * 16 + lc;
    WtB[((ntile * 8 + ks) * 64 + lane) * 8 + j2] = (short)f2bf_bits(v);
    if (kk == 0) {
        __shared__ float t1[128];
        float sh = 0.f, qh = 0.f;
#pragma unroll 8
        for (int j = 0; j < 64; ++j) {
            sh += pp[j * 256 + h];
            qh += pp[j * 256 + 128 + h];
        }
        float mh = sh / Nf;
        float vh = qh / Nf - mh * mh;
        float svh = g[h] * rsqrtf(vh + BN_EPS);
        t1[h] = beta[h] - mh * svh;
        __syncthreads();
        float sb = 0.f;
#pragma unroll 4
        for (int d = 0; d < 128; ++d) sb = fmaf(Wq[h * 128 + d], t1[d], sb);
        if (k == 0) {
            bias[h] = b_ma1[h];
            bias[128 + h] = sb + c1_r[h];
        } else {
            bias[256 + h] = sb + c1_p[h];
        }
    }
}

// ---------------------------------------------------------------------------
// finalize2: from pp2 stats, emit WtBo frags (K=128) + b_out.
// ---------------------------------------------------------------------------
__global__ __launch_bounds__(128) void finalize2_k(
    const float* __restrict__ pp, const float* __restrict__ w_ma2,
    const float* __restrict__ b_ma2, const float* __restrict__ g,
    const float* __restrict__ beta, float Nf, short* __restrict__ WtBo,
    float* __restrict__ b_out) {
    int k = blockIdx.x, h = threadIdx.x;
    float ssum = 0.f, ssq = 0.f;
#pragma unroll 8
    for (int j = 0; j < 64; ++j) {
        ssum += pp[j * 256 + k];
        ssq += pp[j * 256 + 128 + k];
    }
    float mean = ssum / Nf;
    float var = ssq / Nf - mean * mean;
    float sv = g[k] * rsqrtf(var + BN_EPS);
    float v = w_ma2[h * 128 + k] * sv;
    int ks = k >> 5, hi = (k >> 3) & 3, j2 = k & 7;
    int ntile = h >> 4, lc = h & 15, lane = hi * 16 + lc;
    WtBo[((ntile * 4 + ks) * 64 + lane) * 8 + j2] = (short)f2bf_bits(v);
    if (k == 0) {
        __shared__ float t2[128];
        float sh = 0.f, qh = 0.f;
#pragma unroll 8
        for (int j = 0; j < 64; ++j) {
            sh += pp[j * 256 + h];
            qh += pp[j * 256 + 128 + h];
        }
        float mh = sh / Nf;
        float vh = qh / Nf - mh * mh;
        float svh = g[h] * rsqrtf(vh + BN_EPS);
        t2[h] = beta[h] - mh * svh;
        __syncthreads();
        float sb = 0.f;
#pragma unroll 4
        for (int d = 0; d < 128; ++d) sb = fmaf(w_ma2[h * 128 + d], t2[d], sb);
        b_out[h] = sb + b_ma2[h];
    }
}

// ---------------------------------------------------------------------------
// dense MFMA GEMM (GEMM5): Out[n,0:128] = bf16(A[n,0:128]) @ W + bias
// AT = float (in-place safe: A staged to LDS before stores) or bf16.
// ---------------------------------------------------------------------------
template <typename AT>
__global__ __launch_bounds__(512, 4) void gemm_dense_mfma(
    const AT* A, const short* __restrict__ WtB,
    const float* __restrict__ biasv, float* Out) {
    __shared__ alignas(16) short Asm[64][136];
    const int t = threadIdx.x, n0 = blockIdx.x * 64;
    const int lane = t & 63, w = t >> 6;
    const int lrow = lane & 15, lhi = lane >> 4;

    {
        int row = t >> 3, g8 = t & 7;
        u32* aw = (u32*)&Asm[0][0];
        int wb = row * 68 + g8 * 8;
        if constexpr (sizeof(AT) == 4) {
            const float* p = (const float*)A + (size_t)(n0 + row) * 128 + g8 * 16;
#pragma unroll
            for (int c = 0; c < 2; ++c) {
                float4 a = *(const float4*)(p + c * 8);
                float4 b2 = *(const float4*)(p + c * 8 + 4);
                u32 pk0 = f2bf_bits(a.x) | (f2bf_bits(a.y) << 16);
                u32 pk1 = f2bf_bits(a.z) | (f2bf_bits(a.w) << 16);
                u32 pk2 = f2bf_bits(b2.x) | (f2bf_bits(b2.y) << 16);
                u32 pk3 = f2bf_bits(b2.z) | (f2bf_bits(b2.w) << 16);
                *(uint4*)&aw[wb + c * 4] = make_uint4(pk0, pk1, pk2, pk3);
            }
        } else {
            const __hip_bfloat16* p = (const __hip_bfloat16*)A + (size_t)(n0 + row) * 128 + g8 * 16;
            uint4 q0 = *(const uint4*)p;
            uint4 q1 = *(const uint4*)(p + 8);
            *(uint4*)&aw[wb] = q0;
            *(uint4*)&aw[wb + 4] = q1;
        }
    }
    short8 bfrag[4];
#pragma unroll
    for (int ks = 0; ks < 4; ++ks)
        bfrag[ks] = *(const short8*)(WtB + (size_t)((w * 4 + ks) * 64 + lane) * 8);
    __syncthreads();

    f32x4 acc[4];
#pragma unroll
    for (int rt = 0; rt < 4; ++rt) acc[rt] = (f32x4){0.f, 0.f, 0.f, 0.f};
#pragma unroll
    for (int rt = 0; rt < 4; ++rt)
#pragma unroll
        for (int ks = 0; ks < 4; ++ks) {
            short8 af = *(const short8*)&Asm[rt * 16 + lrow][ks * 32 + lhi * 8];
            acc[rt] = MFMA16(af, bfrag[ks], acc[rt]);
        }
    int col = w * 16 + lrow;
    float bb = biasv[col];
#pragma unroll
    for (int rt = 0; rt < 4; ++rt)
#pragma unroll
        for (int i = 0; i < 4; ++i) {
            int row = rt * 16 + lhi * 4 + i;
            Out[(size_t)(n0 + row) * 128 + col] = acc[rt][i] + bb;
        }
}

// ---------------------------------------------------------------------------
// MFMA gather GEMM (R8 geometry + degree-sorted bin permutation).
// node-major src [nsrc, B=8, 128] bf16. Block = 8 perm'd bins x 8 batches,
// 512 threads = 8 waves; wave w owns bin perm[blockIdx*8+w]. lane:
// batch=lane>>3, ck=lane&7; one 2KB burst per edge; both halves interleaved.
// Outputs written at canonical bin addresses (full 2KB/512B chunks).
// PERM: Out row = batch*permN + bin (batch-major); else bin*8 + batch.
// ---------------------------------------------------------------------------
template <typename OT, bool PERM>
__global__ __launch_bounds__(512, 4) void gemm_gather_mfma(
    const __hip_bfloat16* __restrict__ src, const int* __restrict__ perm,
    const int* __restrict__ off1, const int* __restrict__ idx1,
    const int* __restrict__ off2, const int* __restrict__ idx2,
    const short* __restrict__ WtB, const float* __restrict__ biasv,
    OT* __restrict__ Out, int permN, float* __restrict__ part) {
    __shared__ alignas(16) short Asm[64][264];
    __shared__ float m1s[64], m2s[64];
    __shared__ int pbins[8];
    const int t = threadIdx.x;
    const int lane = t & 63;
    const int w = __builtin_amdgcn_readfirstlane(t >> 6);
    const int lrow = lane & 15, lhi = lane >> 4;

    const int rb = perm[blockIdx.x * 8 + w];
    if (lane == 0) pbins[w] = rb;

    // B fragments early (in flight during gather); wave w -> col-tile w
    short8 bfrag[8];
#pragma unroll
    for (int ks = 0; ks < 8; ++ks)
        bfrag[ks] = *(const short8*)(WtB + (size_t)((w * 8 + ks) * 64 + lane) * 8);

    // ---- gather: wave w -> bin rb; both halves interleaved ----
    {
        const int batch = lane >> 3, ck = lane & 7;
        const int arow = w * 8 + batch;
        const __hip_bfloat16* lsrc = src + batch * 128 + ck * 16;
        int ea = off1[rb];
        const int e1a = off1[rb + 1];
        int eb = off2[rb];
        const int e1b = off2[rb + 1];
        const int cnta = e1a - ea, cntb = e1b - eb;
        float ga[16], gb[16];
#pragma unroll
        for (int j = 0; j < 16; ++j) { ga[j] = 0.f; gb[j] = 0.f; }
        while (ea < e1a && eb < e1b) {
            int ia = idx1[ea++];
            int ib = idx2[eb++];
            acc16(lsrc + (size_t)ia * 1024, ga);
            acc16(lsrc + (size_t)ib * 1024, gb);
        }
        for (; ea + 2 <= e1a; ea += 2) {
            int i0 = idx1[ea], i1 = idx1[ea + 1];
            acc16(lsrc + (size_t)i0 * 1024, ga);
            acc16(lsrc + (size_t)i1 * 1024, ga);
        }
        if (ea < e1a) acc16(lsrc + (size_t)idx1[ea] * 1024, ga);
        for (; eb + 2 <= e1b; eb += 2) {
            int i0 = idx2[eb], i1 = idx2[eb + 1];
            acc16(lsrc + (size_t)i0 * 1024, gb);
            acc16(lsrc + (size_t)i1 * 1024, gb);
        }
        if (eb < e1b) acc16(lsrc + (size_t)idx2[eb] * 1024, gb);

        float sca = (cnta > 0) ? 1.f / (float)cnta : 0.f;
        float scb = (cntb > 0) ? 1.f / (float)cntb : 0.f;
        if (ck == 0) {
            m1s[arow] = (cnta > 0) ? 1.f : 0.f;
            m2s[arow] = (cntb > 0) ? 1.f : 0.f;
        }
        u32* aw = (u32*)&Asm[0][0];
        int wba = arow * 132 + ck * 8;
        u32 pk[8];
#pragma unroll
        for (int q = 0; q < 8; ++q)
            pk[q] = f2bf_bits(ga[q * 2] * sca) | (f2bf_bits(ga[q * 2 + 1] * sca) << 16);
        *(uint4*)&aw[wba] = make_uint4(pk[0], pk[1], pk[2], pk[3]);
        *(uint4*)&aw[wba + 4] = make_uint4(pk[4], pk[5], pk[6], pk[7]);
#pragma unroll
        for (int q = 0; q < 8; ++q)
            pk[q] = f2bf_bits(gb[q * 2] * scb) | (f2bf_bits(gb[q * 2 + 1] * scb) << 16);
        *(uint4*)&aw[wba + 64] = make_uint4(pk[0], pk[1], pk[2], pk[3]);
        *(uint4*)&aw[wba + 68] = make_uint4(pk[4], pk[5], pk[6], pk[7]);
    }
    __syncthreads();

    // ---- MFMA: 4 row-tiles x 8 k-steps; wave w -> col-tile w ----
    f32x4 acc[4];
#pragma unroll
    for (int rt = 0; rt < 4; ++rt) acc[rt] = (f32x4){0.f, 0.f, 0.f, 0.f};
#pragma unroll
    for (int rt = 0; rt < 4; ++rt)
#pragma unroll
        for (int ks = 0; ks < 8; ++ks) {
            short8 af = *(const short8*)&Asm[rt * 16 + lrow][ks * 32 + lhi * 8];
            acc[rt] = MFMA16(af, bfrag[ks], acc[rt]);
        }

    // ---- epilogue ----
    const int col = w * 16 + lrow;
    float bb = biasv[col], bm1 = biasv[128 + col], bm2 = biasv[256 + col];
    float ps = 0.f, pq = 0.f;
#pragma unroll
    for (int rt = 0; rt < 4; ++rt)
#pragma unroll
        for (int i = 0; i < 4; ++i) {
            int row = rt * 16 + lhi * 4 + i;
            float v = acc[rt][i] + bb + m1s[row] * bm1 + m2s[row] * bm2;
            v = fmaxf(v, 0.f);
            ps += v;
            pq += v * v;
            int bin = pbins[row >> 3];
            size_t orow = PERM ? ((size_t)(row & 7) * permN + bin)
                               : ((size_t)bin * 8 + (row & 7));
            storev(&Out[orow * 128 + col], v);
        }
    ps += __shfl_xor(ps, 16);
    ps += __shfl_xor(ps, 32);
    pq += __shfl_xor(pq, 16);
    pq += __shfl_xor(pq, 32);
    if (lhi == 0) {
        part[(size_t)blockIdx.x * 256 + col] = ps;
        part[(size_t)blockIdx.x * 256 + 128 + col] = pq;
    }
}

// ---------------------------------------------------------------------------
// launch
// ---------------------------------------------------------------------------
extern "C" void kernel_launch(void* const* d_in, const int* in_sizes, int n_in,
                              void* d_out, int out_size, void* d_ws, size_t ws_size,
                              hipStream_t stream) {
    const float* nodes = (const float*)d_in[0];
    const int* r2e = (const int*)d_in[1];
    const int* p2e = (const int*)d_in[2];
    const int* e2r = (const int*)d_in[3];
    const int* e2p = (const int*)d_in[4];
    const float* w_rct = (const float*)d_in[5];
    const float* b_rct = (const float*)d_in[6];
    const float* w_prd = (const float*)d_in[7];
    const float* b_prd = (const float*)d_in[8];
    const float* w_ra1 = (const float*)d_in[9];
    const float* b_ra1 = (const float*)d_in[10];
    const float* bn_r_g = (const float*)d_in[11];
    const float* bn_r_b = (const float*)d_in[12];
    const float* w_ra2 = (const float*)d_in[13];
    const float* b_ra2 = (const float*)d_in[14];
    const float* w_r2rct = (const float*)d_in[15];
    const float* b_r2rct = (const float*)d_in[16];
    const float* w_r2prd = (const float*)d_in[17];
    const float* b_r2prd = (const float*)d_in[18];
    const float* w_ma1 = (const float*)d_in[19];
    const float* b_ma1 = (const float*)d_in[20];
    const float* bn_m_g = (const float*)d_in[21];
    const float* bn_m_b = (const float*)d_in[22];
    const float* w_ma2 = (const float*)d_in[23];
    const float* b_ma2 = (const float*)d_in[24];

    char* ws = (char*)d_ws;
    size_t off = 0;
    auto alloc = [&](size_t bytes) -> char* {
        off = (off + 255) & ~(size_t)255;
        char* p = ws + off;
        off += bytes;
        return p;
    };

    const size_t H1B = (size_t)NR * NB * 128 * 2;  // 102.4 MB node-major [R,B,128]
    __hip_bfloat16* h1 = (__hip_bfloat16*)alloc(H1B);

    // counters block (zeroed): 4 counts + 4 cursors + 2 hist64 + 2 cur64
    const size_t CNTI = (size_t)2 * (NR + NR + NM + NM) + 256;
    char* cntcur = alloc(CNTI * 4);
    int* cnt_r = (int*)cntcur;
    int* cnt_p = cnt_r + NR;
    int* cnt_er = cnt_p + NR;
    int* cnt_ep = cnt_er + NM;
    int* cur_r = cnt_ep + NM;
    int* cur_p = cur_r + NR;
    int* cur_er = cur_p + NR;
    int* cur_ep = cur_er + NM;
    int* hist_r = cur_ep + NM;
    int* hist_m = hist_r + 64;
    int* cur64_r = hist_m + 64;
    int* cur64_m = cur64_r + 64;

    int* off_r = (int*)alloc((NR + 1) * 4);
    int* off_p = (int*)alloc((NR + 1) * 4);
    int* off_er = (int*)alloc((NM + 1) * 4);
    int* off_ep = (int*)alloc((NM + 1) * 4);
    int* idx_r = (int*)alloc(NE * 4);
    int* idx_p = (int*)alloc(NE * 4);
    int* idx_er = (int*)alloc(NE * 4);
    int* idx_ep = (int*)alloc(NE * 4);
    int* deg_r = (int*)alloc(NR * 4);
    int* deg_m = (int*)alloc(NM * 4);
    int* perm_r = (int*)alloc(NR * 4);
    int* perm_m = (int*)alloc(NM * 4);

    float* bias1 = (float*)alloc(3 * 128 * 4);
    float* bias2 = (float*)alloc(3 * 128 * 4);
    float* b_out = (float*)alloc(128 * 4);
    float* Wq_r = (float*)alloc(128 * 128 * 4);
    float* Wq_p = (float*)alloc(128 * 128 * 4);
    float* c1_r = (float*)alloc(128 * 4);
    float* c1_p = (float*)alloc(128 * 4);
    short* WtB1 = (short*)alloc(256 * 128 * 2);
    short* WtB2 = (short*)alloc(256 * 128 * 2);
    short* WtBo = (short*)alloc(128 * 128 * 2);
    const int NBLK1 = NR / 8;  // 6250
    const int NBLK2 = NM / 8;  // 2500
    float* part1 = (float*)alloc((size_t)NBLK1 * 256 * 4);  // 6.4 MB
    float* part2 = part1;                                   // sequential reuse
    float* pp1 = (float*)alloc(64 * 256 * 4);
    float* pp2 = pp1;  // sequential reuse

    // optional bf16 h2 buffer (only used if workspace is large enough)
    __hip_bfloat16* h2bf = (__hip_bfloat16*)alloc((size_t)NB * NM * 128 * 2);
    const bool bf16h2 = (off <= ws_size);

    // nb16 [M,B,128] bf16 (41 MB) lives in d_out (dead after gather1)
    __hip_bfloat16* nb16 = (__hip_bfloat16*)d_out;

    hipMemsetAsync(cntcur, 0, CNTI * 4, stream);

    // ---- CSR build (fused) + degree sort ----
    const int EB = (NE + 255) / 256;
    hist4_k<<<dim3(EB, 4), 256, 0, stream>>>(r2e, p2e, e2r, e2p,
                                             cnt_r, cnt_p, cnt_er, cnt_ep);
    scan4_k<<<4, 1024, 0, stream>>>(cnt_r, off_r, NR, cnt_p, off_p, NR,
                                    cnt_er, off_er, NM, cnt_ep, off_ep, NM);
    fill4_k<<<dim3(EB, 4), 256, 0, stream>>>(r2e, p2e, e2r, e2p,
                                             off_r, off_p, off_er, off_ep,
                                             cur_r, cur_p, cur_er, cur_ep,
                                             idx_r, idx_p, idx_er, idx_ep);
    const int DB = (NR + 255) / 256;
    deghist_k<<<dim3(DB, 2), 256, 0, stream>>>(off_r, off_p, NR, deg_r, hist_r,
                                               off_er, off_ep, NM, deg_m, hist_m);
    permscatter_k<<<dim3(DB, 2), 256, 0, stream>>>(
        deg_r, hist_r, cur64_r, perm_r, NR, deg_m, hist_m, cur64_m, perm_m, NM);

    // ---- fused admin: cast + WtB1/bias1 + Wq chain ----
    prep_all_k<<<NCAST + 384, 256, 0, stream>>>(
        nodes, nb16, w_rct, w_prd, w_ra1, b_rct, b_prd, b_ra1, WtB1, bias1,
        w_ma1, w_r2rct, w_r2prd, b_r2rct, b_r2prd, w_ra2, b_ra2,
        Wq_r, Wq_p, c1_r, c1_p);

    // ---- GEMM2 (gather): h1 = relu(gather(nb16)@Wt1 + biases) + BN1 partials ----
    gemm_gather_mfma<__hip_bfloat16, false><<<NBLK1, 512, 0, stream>>>(
        nb16, perm_r, off_r, idx_r, off_p, idx_p, WtB1, bias1, h1, 0, part1);
    reduce_part_k<<<64, 256, 0, stream>>>(part1, NBLK1, (NBLK1 + 63) / 64, pp1);
    finalize1_k<<<256, 128, 0, stream>>>(pp1, Wq_r, Wq_p, c1_r, c1_p, b_ma1,
                                         bn_r_g, bn_r_b, (float)((size_t)NB * NR),
                                         WtB2, bias2);

    // ---- GEMM4 (gather): h2 = relu(gather(h1)@Wt2 + biases) + BN2 partials ----
    if (bf16h2) {
        gemm_gather_mfma<__hip_bfloat16, true><<<NBLK2, 512, 0, stream>>>(
            h1, perm_m, off_er, idx_er, off_ep, idx_ep, WtB2, bias2, h2bf, NM, part2);
    } else {
        gemm_gather_mfma<float, true><<<NBLK2, 512, 0, stream>>>(
            h1, perm_m, off_er, idx_er, off_ep, idx_ep, WtB2, bias2,
            (float*)d_out, NM, part2);
    }
    reduce_part_k<<<64, 256, 0, stream>>>(part2, NBLK2, (NBLK2 + 63) / 64, pp2);
    finalize2_k<<<128, 128, 0, stream>>>(pp2, w_ma2, b_ma2, bn_m_g, bn_m_b,
                                         (float)((size_t)NB * NM), WtBo, b_out);

    // ---- GEMM5 (MFMA) -> d_out ----
    if (bf16h2) {
        gemm_dense_mfma<__hip_bfloat16><<<(NB * NM) / 64, 512, 0, stream>>>(
            h2bf, WtBo, b_out, (float*)d_out);
    } else {
        gemm_dense_mfma<float><<<(NB * NM) / 64, 512, 0, stream>>>(
            (float*)d_out, WtBo, b_out, (float*)d_out);
    }
}

// Round 10
// 434.596 us; speedup vs baseline: 1.7965x; 1.7965x over previous
//
#include <hip/hip_runtime.h>
#include <hip/hip_bf16.h>

#define NB 8
#define NM 20000
#define NR 50000
#define NE 100000
#define BN_EPS 1e-5f

typedef unsigned int u32;

using short8 = __attribute__((ext_vector_type(8))) short;  // 8 bf16
using f32x4 = __attribute__((ext_vector_type(4))) float;

#define MFMA16(a, b, c) __builtin_amdgcn_mfma_f32_16x16x32_bf16(a, b, c, 0, 0, 0)

__device__ inline u32 f2bf_bits(float f) {
    u32 x = __float_as_uint(f);
    return (x + 0x7fffu + ((x >> 16) & 1u)) >> 16;
}
__device__ inline void storev(float* p, float v) { *p = v; }
__device__ inline void storev(__hip_bfloat16* p, float v) {
    *(unsigned short*)p = (unsigned short)f2bf_bits(v);
}

// accumulate 16 bf16 cols (32B) into fp32
__device__ inline void acc16(const __hip_bfloat16* p, float* g) {
    uint4 q0 = *(const uint4*)p;
    uint4 q1 = *(const uint4*)(p + 8);
    u32 ww[8] = {q0.x, q0.y, q0.z, q0.w, q1.x, q1.y, q1.z, q1.w};
#pragma unroll
    for (int q = 0; q < 8; ++q) {
        g[q * 2] += __uint_as_float(ww[q] << 16);
        g[q * 2 + 1] += __uint_as_float(ww[q] & 0xFFFF0000u);
    }
}

// ---------------------------------------------------------------------------
// CSR build (fused 4-list histogram / fill)
// ---------------------------------------------------------------------------
__global__ __launch_bounds__(256) void hist4_k(const int* __restrict__ l0,
                                               const int* __restrict__ l1,
                                               const int* __restrict__ l2,
                                               const int* __restrict__ l3,
                                               int* c0, int* c1, int* c2, int* c3) {
    int i = blockIdx.x * 256 + threadIdx.x;
    if (i >= NE) return;
    const int* e;
    int* c;
    switch (blockIdx.y) {
        case 0: e = l0; c = c0; break;
        case 1: e = l1; c = c1; break;
        case 2: e = l2; c = c2; break;
        default: e = l3; c = c3; break;
    }
    atomicAdd(&c[e[NE + i]], 1);
}

__global__ __launch_bounds__(256) void fill4_k(
    const int* __restrict__ l0, const int* __restrict__ l1,
    const int* __restrict__ l2, const int* __restrict__ l3,
    const int* __restrict__ o0, const int* __restrict__ o1,
    const int* __restrict__ o2, const int* __restrict__ o3,
    int* u0, int* u1, int* u2, int* u3,
    int* x0, int* x1, int* x2, int* x3) {
    int i = blockIdx.x * 256 + threadIdx.x;
    if (i >= NE) return;
    const int *e, *o;
    int *cur, *idx;
    switch (blockIdx.y) {
        case 0: e = l0; o = o0; cur = u0; idx = x0; break;
        case 1: e = l1; o = o1; cur = u1; idx = x1; break;
        case 2: e = l2; o = o2; cur = u2; idx = x2; break;
        default: e = l3; o = o3; cur = u3; idx = x3; break;
    }
    int d = e[NE + i];
    int p = atomicAdd(&cur[d], 1);
    idx[o[d] + p] = e[i];
}

__global__ __launch_bounds__(1024) void scan4_k(
    const int* c0, int* o0, int n0, const int* c1, int* o1, int n1,
    const int* c2, int* o2, int n2, const int* c3, int* o3, int n3) {
    const int* c; int* o; int n;
    if (blockIdx.x == 0) { c = c0; o = o0; n = n0; }
    else if (blockIdx.x == 1) { c = c1; o = o1; n = n1; }
    else if (blockIdx.x == 2) { c = c2; o = o2; n = n2; }
    else { c = c3; o = o3; n = n3; }
    __shared__ int wsum[16];
    __shared__ int carry_s;
    int t = threadIdx.x, lane = t & 63, w = t >> 6;
    if (t == 0) carry_s = 0;
    __syncthreads();
    for (int base = 0; base < n; base += 1024) {
        int i = base + t;
        int x = (i < n) ? c[i] : 0;
#pragma unroll
        for (int s = 1; s < 64; s <<= 1) {
            int y = __shfl_up(x, s);
            if (lane >= s) x += y;
        }
        if (lane == 63) wsum[w] = x;
        __syncthreads();
        if (w == 0) {
            int ws = (lane < 16) ? wsum[lane] : 0;
#pragma unroll
            for (int s = 1; s < 16; s <<= 1) {
                int y = __shfl_up(ws, s);
                if (lane >= s) ws += y;
            }
            if (lane < 16) wsum[lane] = ws;
        }
        __syncthreads();
        int wbase = (w > 0) ? wsum[w - 1] : 0;
        int incl = x + wbase + carry_s;
        if (i < n) o[i + 1] = incl;
        __syncthreads();
        if (t == 1023) carry_s = incl;
        __syncthreads();
    }
    if (t == 0) o[0] = 0;
}

// ---------------------------------------------------------------------------
// degree sort, atomic-cold 3-pass counting sort (no hot global atomics):
//  1) per-block LDS histogram -> bh[blk][64]
//  2) one wave per list: cross-block exclusive prefix per bin + bin bases
//  3) scatter with LDS-atomic local rank
// ---------------------------------------------------------------------------
__global__ __launch_bounds__(256) void deg_blkhist_k(
    const int* __restrict__ o1a, const int* __restrict__ o2a, int na,
    int* __restrict__ dega, int* __restrict__ bha,
    const int* __restrict__ o1b, const int* __restrict__ o2b, int nb,
    int* __restrict__ degb, int* __restrict__ bhb) {
    int list = blockIdx.y;
    const int* o1 = list ? o1b : o1a;
    const int* o2 = list ? o2b : o2a;
    int n = list ? nb : na;
    int* deg = list ? degb : dega;
    int* bh = list ? bhb : bha;
    if (blockIdx.x * 256 >= n) return;
    __shared__ int lh[64];
    int t = threadIdx.x;
    if (t < 64) lh[t] = 0;
    __syncthreads();
    int i = blockIdx.x * 256 + t;
    if (i < n) {
        int d = min((o1[i + 1] - o1[i]) + (o2[i + 1] - o2[i]), 63);
        deg[i] = d;
        atomicAdd(&lh[d], 1);  // LDS atomic: 64 slots, low contention
    }
    __syncthreads();
    if (t < 64) bh[blockIdx.x * 64 + t] = lh[t];
}

__global__ __launch_bounds__(64) void scan_bins_k(int* __restrict__ bha, int nblka,
                                                  int* __restrict__ bhb, int nblkb) {
    int* bh = blockIdx.x ? bhb : bha;
    int nblk = blockIdx.x ? nblkb : nblka;
    int t = threadIdx.x;  // bin 0..63
    int run = 0;
    for (int b = 0; b < nblk; ++b) {
        int c = bh[b * 64 + t];
        bh[b * 64 + t] = run;  // exclusive prefix within bin
        run += c;
    }
    int x = run;  // exclusive scan of bin totals across 64 lanes
#pragma unroll
    for (int s = 1; s < 64; s <<= 1) {
        int y = __shfl_up(x, s);
        if (t >= s) x += y;
    }
    int base = x - run;
    for (int b = 0; b < nblk; ++b) bh[b * 64 + t] += base;
}

__global__ __launch_bounds__(256) void scatter_perm_k(
    const int* __restrict__ dega, const int* __restrict__ bha,
    int* __restrict__ perma, int na,
    const int* __restrict__ degb, const int* __restrict__ bhb,
    int* __restrict__ permb, int nb) {
    int list = blockIdx.y;
    const int* deg = list ? degb : dega;
    const int* bh = list ? bhb : bha;
    int* perm = list ? permb : perma;
    int n = list ? nb : na;
    if (blockIdx.x * 256 >= n) return;
    __shared__ int lh[64];
    int t = threadIdx.x;
    if (t < 64) lh[t] = 0;
    __syncthreads();
    int i = blockIdx.x * 256 + t;
    int d = 0, r = 0;
    if (i < n) {
        d = deg[i];
        r = atomicAdd(&lh[d], 1);  // LDS atomic
    }
    __syncthreads();
    if (i < n) perm[bh[blockIdx.x * 64 + d] + r] = i;
}

// ---------------------------------------------------------------------------
// prep_all: grid-fused admin.
//  blk <  NCAST              : nodes [B,M,128] f32 -> node-major bf16 [M,B,128]
//  blk in [NCAST, +128)      : WtB1 frags + bias1 (2 k per block)
//  blk in [NCAST+128, +256)  : Wq_x = (w_ma1@w_r2x)@w_ra2 ; c1_x (per row h)
// ---------------------------------------------------------------------------
#define NCAST 10000
__global__ __launch_bounds__(256) void prep_all_k(
    const float* __restrict__ nodes, __hip_bfloat16* __restrict__ nb16,
    const float* __restrict__ w_rct, const float* __restrict__ w_prd,
    const float* __restrict__ w_ra1, const float* __restrict__ b_rct,
    const float* __restrict__ b_prd, const float* __restrict__ b_ra1,
    short* __restrict__ WtB1, float* __restrict__ bias1,
    const float* __restrict__ w_ma1, const float* __restrict__ w_r2rct,
    const float* __restrict__ w_r2prd, const float* __restrict__ b_r2rct,
    const float* __restrict__ b_r2prd, const float* __restrict__ w_ra2,
    const float* __restrict__ b_ra2, float* __restrict__ Wq_r,
    float* __restrict__ Wq_p, float* __restrict__ c1_r, float* __restrict__ c1_p) {
    __shared__ float smem[384];
    const int blk = blockIdx.x, t = threadIdx.x;
    if (blk < NCAST) {  // cast section
        int id = blk * 256 + t;
        int c8 = (id & 15) * 8;
        int b = (id >> 4) & 7;
        int m = id >> 7;
        const float* p = nodes + ((size_t)b * NM + m) * 128 + c8;
        float4 a = *(const float4*)p;
        float4 b2 = *(const float4*)(p + 4);
        u32 pk0 = f2bf_bits(a.x) | (f2bf_bits(a.y) << 16);
        u32 pk1 = f2bf_bits(a.z) | (f2bf_bits(a.w) << 16);
        u32 pk2 = f2bf_bits(b2.x) | (f2bf_bits(b2.y) << 16);
        u32 pk3 = f2bf_bits(b2.z) | (f2bf_bits(b2.w) << 16);
        *(uint4*)(nb16 + ((size_t)m * 8 + b) * 128 + c8) = make_uint4(pk0, pk1, pk2, pk3);
        return;
    }
    if (blk < NCAST + 128) {  // WtB1 frags: k = (blk-NCAST)*2 + (t>>7)
        float (*col2)[128] = (float(*)[128])smem;
        int half = t >> 7, h = t & 127;
        int k = (blk - NCAST) * 2 + half;
        const float* wsrc = (k < 128) ? w_rct : w_prd;
        int kk = k & 127;
        col2[half][h] = wsrc[h * 128 + kk];
        __syncthreads();
        float s = 0.f;
#pragma unroll 4
        for (int j = 0; j < 128; ++j) s = fmaf(w_ra1[h * 128 + j], col2[half][j], s);
        int ks = k >> 5, hi = (k >> 3) & 3, j2 = k & 7;
        int ntile = h >> 4, lc = h & 15, lane = hi * 16 + lc;
        WtB1[((ntile * 8 + ks) * 64 + lane) * 8 + j2] = (short)f2bf_bits(s);
        if (k == 0) {
            float sb1 = 0.f, sb2 = 0.f;
            for (int j = 0; j < 128; ++j) {
                float w = w_ra1[h * 128 + j];
                sb1 = fmaf(w, b_rct[j], sb1);
                sb2 = fmaf(w, b_prd[j], sb2);
            }
            bias1[h] = b_ra1[h];
            bias1[128 + h] = sb1;
            bias1[256 + h] = sb2;
        }
        return;
    }
    // Wq chain section
    float* rowv = smem;
    float* Prow = smem + 128;
    float* red = smem + 256;
    int blk2 = blk - (NCAST + 128);
    bool sec = blk2 >= 128;
    int h = blk2 & 127;
    const float* wr2 = sec ? w_r2prd : w_r2rct;
    const float* br2 = sec ? b_r2prd : b_r2rct;
    float* Wq = sec ? Wq_p : Wq_r;
    float* c1 = sec ? c1_p : c1_r;
    if (t < 128) rowv[t] = w_ma1[h * 128 + t];
    __syncthreads();
    if (t < 128) {
        float s = 0.f;
#pragma unroll 4
        for (int j = 0; j < 128; ++j) s = fmaf(rowv[j], wr2[j * 128 + t], s);
        Prow[t] = s;
        red[t] = rowv[t] * br2[t];
    }
    __syncthreads();
    for (int o = 64; o > 0; o >>= 1) {
        if (t < o) red[t] += red[t + o];
        __syncthreads();
    }
    float c1a = red[0];
    __syncthreads();
    if (t < 128) {
        float s = 0.f;
#pragma unroll 4
        for (int j = 0; j < 128; ++j) s = fmaf(Prow[j], w_ra2[j * 128 + t], s);
        Wq[h * 128 + t] = s;
        red[t] = Prow[t] * b_ra2[t];
    }
    __syncthreads();
    for (int o = 64; o > 0; o >>= 1) {
        if (t < o) red[t] += red[t + o];
        __syncthreads();
    }
    if (t == 0) c1[h] = red[0] + c1a;
}

// ---------------------------------------------------------------------------
// deterministic stat reduction: part[nblk][256] -> pp[64][256]
// ---------------------------------------------------------------------------
__global__ __launch_bounds__(256) void reduce_part_k(const float* __restrict__ part,
                                                     int nblk, int chunk,
                                                     float* __restrict__ pp) {
    int t = threadIdx.x, j = blockIdx.x;
    int r0 = j * chunk;
    int r1 = min(nblk, r0 + chunk);
    float s = 0.f;
    for (int r = r0; r < r1; ++r) s += part[(size_t)r * 256 + t];
    pp[j * 256 + t] = s;
}

// ---------------------------------------------------------------------------
// finalize1: from pp1 stats + precomputed Wq/c1, emit WtB2 frags + bias2.
// ---------------------------------------------------------------------------
__global__ __launch_bounds__(128) void finalize1_k(
    const float* __restrict__ pp, const float* __restrict__ Wq_r,
    const float* __restrict__ Wq_p, const float* __restrict__ c1_r,
    const float* __restrict__ c1_p, const float* __restrict__ b_ma1,
    const float* __restrict__ g, const float* __restrict__ beta, float Nf,
    short* __restrict__ WtB, float* __restrict__ bias) {
    int k = blockIdx.x, h = threadIdx.x, kk = k & 127;
    const float* Wq = (k < 128) ? Wq_r : Wq_p;
    float ssum = 0.f, ssq = 0.f;
#pragma unroll 8
    for (int j = 0; j < 64; ++j) {
        ssum += pp[j * 256 + kk];
        ssq += pp[j * 256 + 128 + kk];
    }
    float mean = ssum / Nf;
    float var = ssq / Nf - mean * mean;
    float sv = g[kk] * rsqrtf(var + BN_EPS);
    float v = Wq[h * 128 + kk] * sv;
    int ks = k >> 5, hi = (k >> 3) & 3, j2 = k & 7;
    int ntile = h >> 4, lc = h & 15, lane = hi * 16 + lc;
    WtB[((ntile * 8 + ks) * 64 + lane) * 8 + j2] = (short)f2bf_bits(v);
    if (kk == 0) {
        __shared__ float t1[128];
        float sh = 0.f, qh = 0.f;
#pragma unroll 8
        for (int j = 0; j < 64; ++j) {
            sh += pp[j * 256 + h];
            qh += pp[j * 256 + 128 + h];
        }
        float mh = sh / Nf;
        float vh = qh / Nf - mh * mh;
        float svh = g[h] * rsqrtf(vh + BN_EPS);
        t1[h] = beta[h] - mh * svh;
        __syncthreads();
        float sb = 0.f;
#pragma unroll 4
        for (int d = 0; d < 128; ++d) sb = fmaf(Wq[h * 128 + d], t1[d], sb);
        if (k == 0) {
            bias[h] = b_ma1[h];
            bias[128 + h] = sb + c1_r[h];
        } else {
            bias[256 + h] = sb + c1_p[h];
        }
    }
}

// ---------------------------------------------------------------------------
// finalize2: from pp2 stats, emit WtBo frags (K=128) + b_out.
// ---------------------------------------------------------------------------
__global__ __launch_bounds__(128) void finalize2_k(
    const float* __restrict__ pp, const float* __restrict__ w_ma2,
    const float* __restrict__ b_ma2, const float* __restrict__ g,
    const float* __restrict__ beta, float Nf, short* __restrict__ WtBo,
    float* __restrict__ b_out) {
    int k = blockIdx.x, h = threadIdx.x;
    float ssum = 0.f, ssq = 0.f;
#pragma unroll 8
    for (int j = 0; j < 64; ++j) {
        ssum += pp[j * 256 + k];
        ssq += pp[j * 256 + 128 + k];
    }
    float mean = ssum / Nf;
    float var = ssq / Nf - mean * mean;
    float sv = g[k] * rsqrtf(var + BN_EPS);
    float v = w_ma2[h * 128 + k] * sv;
    int ks = k >> 5, hi = (k >> 3) & 3, j2 = k & 7;
    int ntile = h >> 4, lc = h & 15, lane = hi * 16 + lc;
    WtBo[((ntile * 4 + ks) * 64 + lane) * 8 + j2] = (short)f2bf_bits(v);
    if (k == 0) {
        __shared__ float t2[128];
        float sh = 0.f, qh = 0.f;
#pragma unroll 8
        for (int j = 0; j < 64; ++j) {
            sh += pp[j * 256 + h];
            qh += pp[j * 256 + 128 + h];
        }
        float mh = sh / Nf;
        float vh = qh / Nf - mh * mh;
        float svh = g[h] * rsqrtf(vh + BN_EPS);
        t2[h] = beta[h] - mh * svh;
        __syncthreads();
        float sb = 0.f;
#pragma unroll 4
        for (int d = 0; d < 128; ++d) sb = fmaf(w_ma2[h * 128 + d], t2[d], sb);
        b_out[h] = sb + b_ma2[h];
    }
}

// ---------------------------------------------------------------------------
// dense MFMA GEMM (GEMM5): Out[n,0:128] = bf16(A[n,0:128]) @ W + bias
// AT = float (in-place safe: A staged to LDS before stores) or bf16.
// ---------------------------------------------------------------------------
template <typename AT>
__global__ __launch_bounds__(512, 4) void gemm_dense_mfma(
    const AT* A, const short* __restrict__ WtB,
    const float* __restrict__ biasv, float* Out) {
    __shared__ alignas(16) short Asm[64][136];
    const int t = threadIdx.x, n0 = blockIdx.x * 64;
    const int lane = t & 63, w = t >> 6;
    const int lrow = lane & 15, lhi = lane >> 4;

    {
        int row = t >> 3, g8 = t & 7;
        u32* aw = (u32*)&Asm[0][0];
        int wb = row * 68 + g8 * 8;
        if constexpr (sizeof(AT) == 4) {
            const float* p = (const float*)A + (size_t)(n0 + row) * 128 + g8 * 16;
#pragma unroll
            for (int c = 0; c < 2; ++c) {
                float4 a = *(const float4*)(p + c * 8);
                float4 b2 = *(const float4*)(p + c * 8 + 4);
                u32 pk0 = f2bf_bits(a.x) | (f2bf_bits(a.y) << 16);
                u32 pk1 = f2bf_bits(a.z) | (f2bf_bits(a.w) << 16);
                u32 pk2 = f2bf_bits(b2.x) | (f2bf_bits(b2.y) << 16);
                u32 pk3 = f2bf_bits(b2.z) | (f2bf_bits(b2.w) << 16);
                *(uint4*)&aw[wb + c * 4] = make_uint4(pk0, pk1, pk2, pk3);
            }
        } else {
            const __hip_bfloat16* p =
                (const __hip_bfloat16*)A + (size_t)(n0 + row) * 128 + g8 * 16;
            uint4 q0 = *(const uint4*)p;
            uint4 q1 = *(const uint4*)(p + 8);
            *(uint4*)&aw[wb] = q0;
            *(uint4*)&aw[wb + 4] = q1;
        }
    }
    short8 bfrag[4];
#pragma unroll
    for (int ks = 0; ks < 4; ++ks)
        bfrag[ks] = *(const short8*)(WtB + (size_t)((w * 4 + ks) * 64 + lane) * 8);
    __syncthreads();

    f32x4 acc[4];
#pragma unroll
    for (int rt = 0; rt < 4; ++rt) acc[rt] = (f32x4){0.f, 0.f, 0.f, 0.f};
#pragma unroll
    for (int rt = 0; rt < 4; ++rt)
#pragma unroll
        for (int ks = 0; ks < 4; ++ks) {
            short8 af = *(const short8*)&Asm[rt * 16 + lrow][ks * 32 + lhi * 8];
            acc[rt] = MFMA16(af, bfrag[ks], acc[rt]);
        }
    int col = w * 16 + lrow;
    float bb = biasv[col];
#pragma unroll
    for (int rt = 0; rt < 4; ++rt)
#pragma unroll
        for (int i = 0; i < 4; ++i) {
            int row = rt * 16 + lhi * 4 + i;
            Out[(size_t)(n0 + row) * 128 + col] = acc[rt][i] + bb;
        }
}

// ---------------------------------------------------------------------------
// MFMA gather GEMM (R8 geometry + degree-sorted bin permutation).
// node-major src [nsrc, B=8, 128] bf16. Block = 8 perm'd bins x 8 batches,
// 512 threads = 8 waves; wave w owns bin perm[blockIdx*8+w]. lane:
// batch=lane>>3, ck=lane&7; one 2KB burst per edge; both halves interleaved.
// Outputs written at canonical bin addresses (full 2KB/512B chunks).
// PERM: Out row = batch*permN + bin (batch-major); else bin*8 + batch.
// ---------------------------------------------------------------------------
template <typename OT, bool PERM>
__global__ __launch_bounds__(512, 4) void gemm_gather_mfma(
    const __hip_bfloat16* __restrict__ src, const int* __restrict__ perm,
    const int* __restrict__ off1, const int* __restrict__ idx1,
    const int* __restrict__ off2, const int* __restrict__ idx2,
    const short* __restrict__ WtB, const float* __restrict__ biasv,
    OT* __restrict__ Out, int permN, float* __restrict__ part) {
    __shared__ alignas(16) short Asm[64][264];
    __shared__ float m1s[64], m2s[64];
    __shared__ int pbins[8];
    const int t = threadIdx.x;
    const int lane = t & 63;
    const int w = __builtin_amdgcn_readfirstlane(t >> 6);
    const int lrow = lane & 15, lhi = lane >> 4;

    const int rb = perm[blockIdx.x * 8 + w];
    if (lane == 0) pbins[w] = rb;

    // B fragments early (in flight during gather); wave w -> col-tile w
    short8 bfrag[8];
#pragma unroll
    for (int ks = 0; ks < 8; ++ks)
        bfrag[ks] = *(const short8*)(WtB + (size_t)((w * 8 + ks) * 64 + lane) * 8);

    // ---- gather: wave w -> bin rb; both halves interleaved ----
    {
        const int batch = lane >> 3, ck = lane & 7;
        const int arow = w * 8 + batch;
        const __hip_bfloat16* lsrc = src + batch * 128 + ck * 16;
        int ea = off1[rb];
        const int e1a = off1[rb + 1];
        int eb = off2[rb];
        const int e1b = off2[rb + 1];
        const int cnta = e1a - ea, cntb = e1b - eb;
        float ga[16], gb[16];
#pragma unroll
        for (int j = 0; j < 16; ++j) { ga[j] = 0.f; gb[j] = 0.f; }
        while (ea < e1a && eb < e1b) {
            int ia = idx1[ea++];
            int ib = idx2[eb++];
            acc16(lsrc + (size_t)ia * 1024, ga);
            acc16(lsrc + (size_t)ib * 1024, gb);
        }
        for (; ea + 2 <= e1a; ea += 2) {
            int i0 = idx1[ea], i1 = idx1[ea + 1];
            acc16(lsrc + (size_t)i0 * 1024, ga);
            acc16(lsrc + (size_t)i1 * 1024, ga);
        }
        if (ea < e1a) acc16(lsrc + (size_t)idx1[ea] * 1024, ga);
        for (; eb + 2 <= e1b; eb += 2) {
            int i0 = idx2[eb], i1 = idx2[eb + 1];
            acc16(lsrc + (size_t)i0 * 1024, gb);
            acc16(lsrc + (size_t)i1 * 1024, gb);
        }
        if (eb < e1b) acc16(lsrc + (size_t)idx2[eb] * 1024, gb);

        float sca = (cnta > 0) ? 1.f / (float)cnta : 0.f;
        float scb = (cntb > 0) ? 1.f / (float)cntb : 0.f;
        if (ck == 0) {
            m1s[arow] = (cnta > 0) ? 1.f : 0.f;
            m2s[arow] = (cntb > 0) ? 1.f : 0.f;
        }
        u32* aw = (u32*)&Asm[0][0];
        int wba = arow * 132 + ck * 8;
        u32 pk[8];
#pragma unroll
        for (int q = 0; q < 8; ++q)
            pk[q] = f2bf_bits(ga[q * 2] * sca) | (f2bf_bits(ga[q * 2 + 1] * sca) << 16);
        *(uint4*)&aw[wba] = make_uint4(pk[0], pk[1], pk[2], pk[3]);
        *(uint4*)&aw[wba + 4] = make_uint4(pk[4], pk[5], pk[6], pk[7]);
#pragma unroll
        for (int q = 0; q < 8; ++q)
            pk[q] = f2bf_bits(gb[q * 2] * scb) | (f2bf_bits(gb[q * 2 + 1] * scb) << 16);
        *(uint4*)&aw[wba + 64] = make_uint4(pk[0], pk[1], pk[2], pk[3]);
        *(uint4*)&aw[wba + 68] = make_uint4(pk[4], pk[5], pk[6], pk[7]);
    }
    __syncthreads();

    // ---- MFMA: 4 row-tiles x 8 k-steps; wave w -> col-tile w ----
    f32x4 acc[4];
#pragma unroll
    for (int rt = 0; rt < 4; ++rt) acc[rt] = (f32x4){0.f, 0.f, 0.f, 0.f};
#pragma unroll
    for (int rt = 0; rt < 4; ++rt)
#pragma unroll
        for (int ks = 0; ks < 8; ++ks) {
            short8 af = *(const short8*)&Asm[rt * 16 + lrow][ks * 32 + lhi * 8];
            acc[rt] = MFMA16(af, bfrag[ks], acc[rt]);
        }

    // ---- epilogue ----
    const int col = w * 16 + lrow;
    float bb = biasv[col], bm1 = biasv[128 + col], bm2 = biasv[256 + col];
    float ps = 0.f, pq = 0.f;
#pragma unroll
    for (int rt = 0; rt < 4; ++rt)
#pragma unroll
        for (int i = 0; i < 4; ++i) {
            int row = rt * 16 + lhi * 4 + i;
            float v = acc[rt][i] + bb + m1s[row] * bm1 + m2s[row] * bm2;
            v = fmaxf(v, 0.f);
            ps += v;
            pq += v * v;
            int bin = pbins[row >> 3];
            size_t orow = PERM ? ((size_t)(row & 7) * permN + bin)
                               : ((size_t)bin * 8 + (row & 7));
            storev(&Out[orow * 128 + col], v);
        }
    ps += __shfl_xor(ps, 16);
    ps += __shfl_xor(ps, 32);
    pq += __shfl_xor(pq, 16);
    pq += __shfl_xor(pq, 32);
    if (lhi == 0) {
        part[(size_t)blockIdx.x * 256 + col] = ps;
        part[(size_t)blockIdx.x * 256 + 128 + col] = pq;
    }
}

// ---------------------------------------------------------------------------
// launch
// ---------------------------------------------------------------------------
extern "C" void kernel_launch(void* const* d_in, const int* in_sizes, int n_in,
                              void* d_out, int out_size, void* d_ws, size_t ws_size,
                              hipStream_t stream) {
    const float* nodes = (const float*)d_in[0];
    const int* r2e = (const int*)d_in[1];
    const int* p2e = (const int*)d_in[2];
    const int* e2r = (const int*)d_in[3];
    const int* e2p = (const int*)d_in[4];
    const float* w_rct = (const float*)d_in[5];
    const float* b_rct = (const float*)d_in[6];
    const float* w_prd = (const float*)d_in[7];
    const float* b_prd = (const float*)d_in[8];
    const float* w_ra1 = (const float*)d_in[9];
    const float* b_ra1 = (const float*)d_in[10];
    const float* bn_r_g = (const float*)d_in[11];
    const float* bn_r_b = (const float*)d_in[12];
    const float* w_ra2 = (const float*)d_in[13];
    const float* b_ra2 = (const float*)d_in[14];
    const float* w_r2rct = (const float*)d_in[15];
    const float* b_r2rct = (const float*)d_in[16];
    const float* w_r2prd = (const float*)d_in[17];
    const float* b_r2prd = (const float*)d_in[18];
    const float* w_ma1 = (const float*)d_in[19];
    const float* b_ma1 = (const float*)d_in[20];
    const float* bn_m_g = (const float*)d_in[21];
    const float* bn_m_b = (const float*)d_in[22];
    const float* w_ma2 = (const float*)d_in[23];
    const float* b_ma2 = (const float*)d_in[24];

    char* ws = (char*)d_ws;
    size_t off = 0;
    auto alloc = [&](size_t bytes) -> char* {
        off = (off + 255) & ~(size_t)255;
        char* p = ws + off;
        off += bytes;
        return p;
    };

    const size_t H1B = (size_t)NR * NB * 128 * 2;  // 102.4 MB node-major [R,B,128]
    __hip_bfloat16* h1 = (__hip_bfloat16*)alloc(H1B);

    // counters block (zeroed): 4 counts + 4 cursors
    const size_t CNTI = (size_t)2 * (NR + NR + NM + NM);
    char* cntcur = alloc(CNTI * 4);
    int* cnt_r = (int*)cntcur;
    int* cnt_p = cnt_r + NR;
    int* cnt_er = cnt_p + NR;
    int* cnt_ep = cnt_er + NM;
    int* cur_r = cnt_ep + NM;
    int* cur_p = cur_r + NR;
    int* cur_er = cur_p + NR;
    int* cur_ep = cur_er + NM;

    int* off_r = (int*)alloc((NR + 1) * 4);
    int* off_p = (int*)alloc((NR + 1) * 4);
    int* off_er = (int*)alloc((NM + 1) * 4);
    int* off_ep = (int*)alloc((NM + 1) * 4);
    int* idx_r = (int*)alloc(NE * 4);
    int* idx_p = (int*)alloc(NE * 4);
    int* idx_er = (int*)alloc(NE * 4);
    int* idx_ep = (int*)alloc(NE * 4);
    int* deg_r = (int*)alloc(NR * 4);
    int* deg_m = (int*)alloc(NM * 4);
    int* perm_r = (int*)alloc(NR * 4);
    int* perm_m = (int*)alloc(NM * 4);
    const int DBR = (NR + 255) / 256;  // 196
    const int DBM = (NM + 255) / 256;  // 79
    int* bh_r = (int*)alloc((size_t)DBR * 64 * 4);
    int* bh_m = (int*)alloc((size_t)DBR * 64 * 4);

    float* bias1 = (float*)alloc(3 * 128 * 4);
    float* bias2 = (float*)alloc(3 * 128 * 4);
    float* b_out = (float*)alloc(128 * 4);
    float* Wq_r = (float*)alloc(128 * 128 * 4);
    float* Wq_p = (float*)alloc(128 * 128 * 4);
    float* c1_r = (float*)alloc(128 * 4);
    float* c1_p = (float*)alloc(128 * 4);
    short* WtB1 = (short*)alloc(256 * 128 * 2);
    short* WtB2 = (short*)alloc(256 * 128 * 2);
    short* WtBo = (short*)alloc(128 * 128 * 2);
    const int NBLK1 = NR / 8;  // 6250
    const int NBLK2 = NM / 8;  // 2500
    float* part1 = (float*)alloc((size_t)NBLK1 * 256 * 4);  // 6.4 MB
    float* part2 = part1;                                   // sequential reuse
    float* pp1 = (float*)alloc(64 * 256 * 4);
    float* pp2 = pp1;  // sequential reuse

    // optional bf16 h2 buffer (only used if workspace is large enough)
    __hip_bfloat16* h2bf = (__hip_bfloat16*)alloc((size_t)NB * NM * 128 * 2);
    const bool bf16h2 = (off <= ws_size);

    // nb16 [M,B,128] bf16 (41 MB) lives in d_out (dead after gather1)
    __hip_bfloat16* nb16 = (__hip_bfloat16*)d_out;

    hipMemsetAsync(cntcur, 0, CNTI * 4, stream);

    // ---- CSR build (fused) ----
    const int EB = (NE + 255) / 256;
    hist4_k<<<dim3(EB, 4), 256, 0, stream>>>(r2e, p2e, e2r, e2p,
                                             cnt_r, cnt_p, cnt_er, cnt_ep);
    scan4_k<<<4, 1024, 0, stream>>>(cnt_r, off_r, NR, cnt_p, off_p, NR,
                                    cnt_er, off_er, NM, cnt_ep, off_ep, NM);
    fill4_k<<<dim3(EB, 4), 256, 0, stream>>>(r2e, p2e, e2r, e2p,
                                             off_r, off_p, off_er, off_ep,
                                             cur_r, cur_p, cur_er, cur_ep,
                                             idx_r, idx_p, idx_er, idx_ep);

    // ---- degree sort (atomic-cold counting sort) ----
    deg_blkhist_k<<<dim3(DBR, 2), 256, 0, stream>>>(
        off_r, off_p, NR, deg_r, bh_r, off_er, off_ep, NM, deg_m, bh_m);
    scan_bins_k<<<2, 64, 0, stream>>>(bh_r, DBR, bh_m, DBM);
    scatter_perm_k<<<dim3(DBR, 2), 256, 0, stream>>>(
        deg_r, bh_r, perm_r, NR, deg_m, bh_m, perm_m, NM);

    // ---- fused admin: cast + WtB1/bias1 + Wq chain ----
    prep_all_k<<<NCAST + 384, 256, 0, stream>>>(
        nodes, nb16, w_rct, w_prd, w_ra1, b_rct, b_prd, b_ra1, WtB1, bias1,
        w_ma1, w_r2rct, w_r2prd, b_r2rct, b_r2prd, w_ra2, b_ra2,
        Wq_r, Wq_p, c1_r, c1_p);

    // ---- GEMM2 (gather): h1 = relu(gather(nb16)@Wt1 + biases) + BN1 partials ----
    gemm_gather_mfma<__hip_bfloat16, false><<<NBLK1, 512, 0, stream>>>(
        nb16, perm_r, off_r, idx_r, off_p, idx_p, WtB1, bias1, h1, 0, part1);
    reduce_part_k<<<64, 256, 0, stream>>>(part1, NBLK1, (NBLK1 + 63) / 64, pp1);
    finalize1_k<<<256, 128, 0, stream>>>(pp1, Wq_r, Wq_p, c1_r, c1_p, b_ma1,
                                         bn_r_g, bn_r_b, (float)((size_t)NB * NR),
                                         WtB2, bias2);

    // ---- GEMM4 (gather): h2 = relu(gather(h1)@Wt2 + biases) + BN2 partials ----
    if (bf16h2) {
        gemm_gather_mfma<__hip_bfloat16, true><<<NBLK2, 512, 0, stream>>>(
            h1, perm_m, off_er, idx_er, off_ep, idx_ep, WtB2, bias2, h2bf, NM, part2);
    } else {
        gemm_gather_mfma<float, true><<<NBLK2, 512, 0, stream>>>(
            h1, perm_m, off_er, idx_er, off_ep, idx_ep, WtB2, bias2,
            (float*)d_out, NM, part2);
    }
    reduce_part_k<<<64, 256, 0, stream>>>(part2, NBLK2, (NBLK2 + 63) / 64, pp2);
    finalize2_k<<<128, 128, 0, stream>>>(pp2, w_ma2, b_ma2, bn_m_g, bn_m_b,
                                         (float)((size_t)NB * NM), WtBo, b_out);

    // ---- GEMM5 (MFMA) -> d_out ----
    if (bf16h2) {
        gemm_dense_mfma<__hip_bfloat16><<<(NB * NM) / 64, 512, 0, stream>>>(
            h2bf, WtBo, b_out, (float*)d_out);
    } else {
        gemm_dense_mfma<float><<<(NB * NM) / 64, 512, 0, stream>>>(
            (float*)d_out, WtBo, b_out, (float*)d_out);
    }
}

// Round 12
// 388.922 us; speedup vs baseline: 2.0075x; 1.1174x over previous
//
#include <hip/hip_runtime.h>
#include <hip/hip_bf16.h>

#define NB 8
#define NM 20000
#define NR 50000
#define NE 100000
#define BN_EPS 1e-5f

typedef unsigned int u32;

using short8 = __attribute__((ext_vector_type(8))) short;  // 8 bf16
using f32x4 = __attribute__((ext_vector_type(4))) float;
using fvec4 = __attribute__((ext_vector_type(4))) float;  // NT-loadable float4

#define MFMA16(a, b, c) __builtin_amdgcn_mfma_f32_16x16x32_bf16(a, b, c, 0, 0, 0)

__device__ inline u32 f2bf_bits(float f) {
    u32 x = __float_as_uint(f);
    return (x + 0x7fffu + ((x >> 16) & 1u)) >> 16;
}
__device__ inline void storev(float* p, float v) { *p = v; }
__device__ inline void storev(__hip_bfloat16* p, float v) {
    *(unsigned short*)p = (unsigned short)f2bf_bits(v);
}
// non-temporal variants: bypass cache allocation (write streams)
__device__ inline void storent(float* p, float v) {
    __builtin_nontemporal_store(v, p);
}
__device__ inline void storent(__hip_bfloat16* p, float v) {
    __builtin_nontemporal_store((unsigned short)f2bf_bits(v), (unsigned short*)p);
}

// accumulate 16 bf16 cols (32B) into fp32
__device__ inline void acc16(const __hip_bfloat16* p, float* g) {
    uint4 q0 = *(const uint4*)p;
    uint4 q1 = *(const uint4*)(p + 8);
    u32 ww[8] = {q0.x, q0.y, q0.z, q0.w, q1.x, q1.y, q1.z, q1.w};
#pragma unroll
    for (int q = 0; q < 8; ++q) {
        g[q * 2] += __uint_as_float(ww[q] << 16);
        g[q * 2 + 1] += __uint_as_float(ww[q] & 0xFFFF0000u);
    }
}

// ---------------------------------------------------------------------------
// CSR build (fused 4-list histogram / fill)
// ---------------------------------------------------------------------------
__global__ __launch_bounds__(256) void hist4_k(const int* __restrict__ l0,
                                               const int* __restrict__ l1,
                                               const int* __restrict__ l2,
                                               const int* __restrict__ l3,
                                               int* c0, int* c1, int* c2, int* c3) {
    int i = blockIdx.x * 256 + threadIdx.x;
    if (i >= NE) return;
    const int* e;
    int* c;
    switch (blockIdx.y) {
        case 0: e = l0; c = c0; break;
        case 1: e = l1; c = c1; break;
        case 2: e = l2; c = c2; break;
        default: e = l3; c = c3; break;
    }
    atomicAdd(&c[e[NE + i]], 1);
}

__global__ __launch_bounds__(256) void fill4_k(
    const int* __restrict__ l0, const int* __restrict__ l1,
    const int* __restrict__ l2, const int* __restrict__ l3,
    const int* __restrict__ o0, const int* __restrict__ o1,
    const int* __restrict__ o2, const int* __restrict__ o3,
    int* u0, int* u1, int* u2, int* u3,
    int* x0, int* x1, int* x2, int* x3) {
    int i = blockIdx.x * 256 + threadIdx.x;
    if (i >= NE) return;
    const int *e, *o;
    int *cur, *idx;
    switch (blockIdx.y) {
        case 0: e = l0; o = o0; cur = u0; idx = x0; break;
        case 1: e = l1; o = o1; cur = u1; idx = x1; break;
        case 2: e = l2; o = o2; cur = u2; idx = x2; break;
        default: e = l3; o = o3; cur = u3; idx = x3; break;
    }
    int d = e[NE + i];
    int p = atomicAdd(&cur[d], 1);
    idx[o[d] + p] = e[i];
}

__global__ __launch_bounds__(1024) void scan4_k(
    const int* c0, int* o0, int n0, const int* c1, int* o1, int n1,
    const int* c2, int* o2, int n2, const int* c3, int* o3, int n3) {
    const int* c; int* o; int n;
    if (blockIdx.x == 0) { c = c0; o = o0; n = n0; }
    else if (blockIdx.x == 1) { c = c1; o = o1; n = n1; }
    else if (blockIdx.x == 2) { c = c2; o = o2; n = n2; }
    else { c = c3; o = o3; n = n3; }
    __shared__ int wsum[16];
    __shared__ int carry_s;
    int t = threadIdx.x, lane = t & 63, w = t >> 6;
    if (t == 0) carry_s = 0;
    __syncthreads();
    for (int base = 0; base < n; base += 1024) {
        int i = base + t;
        int x = (i < n) ? c[i] : 0;
#pragma unroll
        for (int s = 1; s < 64; s <<= 1) {
            int y = __shfl_up(x, s);
            if (lane >= s) x += y;
        }
        if (lane == 63) wsum[w] = x;
        __syncthreads();
        if (w == 0) {
            int ws = (lane < 16) ? wsum[lane] : 0;
#pragma unroll
            for (int s = 1; s < 16; s <<= 1) {
                int y = __shfl_up(ws, s);
                if (lane >= s) ws += y;
            }
            if (lane < 16) wsum[lane] = ws;
        }
        __syncthreads();
        int wbase = (w > 0) ? wsum[w - 1] : 0;
        int incl = x + wbase + carry_s;
        if (i < n) o[i + 1] = incl;
        __syncthreads();
        if (t == 1023) carry_s = incl;
        __syncthreads();
    }
    if (t == 0) o[0] = 0;
}

// ---------------------------------------------------------------------------
// prep_all: grid-fused admin.
//  blk <  NCAST              : nodes [B,M,128] f32 -> node-major bf16 [M,B,128]
//  blk in [NCAST, +128)      : WtB1 frags + bias1 (2 k per block)
//  blk in [NCAST+128, +256)  : Wq_x = (w_ma1@w_r2x)@w_ra2 ; c1_x (per row h)
// ---------------------------------------------------------------------------
#define NCAST 10000
__global__ __launch_bounds__(256) void prep_all_k(
    const float* __restrict__ nodes, __hip_bfloat16* __restrict__ nb16,
    const float* __restrict__ w_rct, const float* __restrict__ w_prd,
    const float* __restrict__ w_ra1, const float* __restrict__ b_rct,
    const float* __restrict__ b_prd, const float* __restrict__ b_ra1,
    short* __restrict__ WtB1, float* __restrict__ bias1,
    const float* __restrict__ w_ma1, const float* __restrict__ w_r2rct,
    const float* __restrict__ w_r2prd, const float* __restrict__ b_r2rct,
    const float* __restrict__ b_r2prd, const float* __restrict__ w_ra2,
    const float* __restrict__ b_ra2, float* __restrict__ Wq_r,
    float* __restrict__ Wq_p, float* __restrict__ c1_r, float* __restrict__ c1_p) {
    __shared__ float smem[384];
    const int blk = blockIdx.x, t = threadIdx.x;
    if (blk < NCAST) {  // cast section (NT loads: nodes is read-once)
        int id = blk * 256 + t;
        int c8 = (id & 15) * 8;
        int b = (id >> 4) & 7;
        int m = id >> 7;
        const float* p = nodes + ((size_t)b * NM + m) * 128 + c8;
        fvec4 a = __builtin_nontemporal_load((const fvec4*)p);
        fvec4 b2 = __builtin_nontemporal_load((const fvec4*)(p + 4));
        u32 pk0 = f2bf_bits(a.x) | (f2bf_bits(a.y) << 16);
        u32 pk1 = f2bf_bits(a.z) | (f2bf_bits(a.w) << 16);
        u32 pk2 = f2bf_bits(b2.x) | (f2bf_bits(b2.y) << 16);
        u32 pk3 = f2bf_bits(b2.z) | (f2bf_bits(b2.w) << 16);
        *(uint4*)(nb16 + ((size_t)m * 8 + b) * 128 + c8) = make_uint4(pk0, pk1, pk2, pk3);
        return;
    }
    if (blk < NCAST + 128) {  // WtB1 frags: k = (blk-NCAST)*2 + (t>>7)
        float (*col2)[128] = (float(*)[128])smem;
        int half = t >> 7, h = t & 127;
        int k = (blk - NCAST) * 2 + half;
        const float* wsrc = (k < 128) ? w_rct : w_prd;
        int kk = k & 127;
        col2[half][h] = wsrc[h * 128 + kk];
        __syncthreads();
        float s = 0.f;
#pragma unroll 4
        for (int j = 0; j < 128; ++j) s = fmaf(w_ra1[h * 128 + j], col2[half][j], s);
        int ks = k >> 5, hi = (k >> 3) & 3, j2 = k & 7;
        int ntile = h >> 4, lc = h & 15, lane = hi * 16 + lc;
        WtB1[((ntile * 8 + ks) * 64 + lane) * 8 + j2] = (short)f2bf_bits(s);
        if (k == 0) {
            float sb1 = 0.f, sb2 = 0.f;
            for (int j = 0; j < 128; ++j) {
                float w = w_ra1[h * 128 + j];
                sb1 = fmaf(w, b_rct[j], sb1);
                sb2 = fmaf(w, b_prd[j], sb2);
            }
            bias1[h] = b_ra1[h];
            bias1[128 + h] = sb1;
            bias1[256 + h] = sb2;
        }
        return;
    }
    // Wq chain section
    float* rowv = smem;
    float* Prow = smem + 128;
    float* red = smem + 256;
    int blk2 = blk - (NCAST + 128);
    bool sec = blk2 >= 128;
    int h = blk2 & 127;
    const float* wr2 = sec ? w_r2prd : w_r2rct;
    const float* br2 = sec ? b_r2prd : b_r2rct;
    float* Wq = sec ? Wq_p : Wq_r;
    float* c1 = sec ? c1_p : c1_r;
    if (t < 128) rowv[t] = w_ma1[h * 128 + t];
    __syncthreads();
    if (t < 128) {
        float s = 0.f;
#pragma unroll 4
        for (int j = 0; j < 128; ++j) s = fmaf(rowv[j], wr2[j * 128 + t], s);
        Prow[t] = s;
        red[t] = rowv[t] * br2[t];
    }
    __syncthreads();
    for (int o = 64; o > 0; o >>= 1) {
        if (t < o) red[t] += red[t + o];
        __syncthreads();
    }
    float c1a = red[0];
    __syncthreads();
    if (t < 128) {
        float s = 0.f;
#pragma unroll 4
        for (int j = 0; j < 128; ++j) s = fmaf(Prow[j], w_ra2[j * 128 + t], s);
        Wq[h * 128 + t] = s;
        red[t] = Prow[t] * b_ra2[t];
    }
    __syncthreads();
    for (int o = 64; o > 0; o >>= 1) {
        if (t < o) red[t] += red[t + o];
        __syncthreads();
    }
    if (t == 0) c1[h] = red[0] + c1a;
}

// ---------------------------------------------------------------------------
// deterministic stat reduction: part[nblk][256] -> pp[64][256]
// ---------------------------------------------------------------------------
__global__ __launch_bounds__(256) void reduce_part_k(const float* __restrict__ part,
                                                     int nblk, int chunk,
                                                     float* __restrict__ pp) {
    int t = threadIdx.x, j = blockIdx.x;
    int r0 = j * chunk;
    int r1 = min(nblk, r0 + chunk);
    float s = 0.f;
    for (int r = r0; r < r1; ++r) s += part[(size_t)r * 256 + t];
    pp[j * 256 + t] = s;
}

// ---------------------------------------------------------------------------
// finalize1: from pp1 stats + precomputed Wq/c1, emit WtB2 frags + bias2.
// ---------------------------------------------------------------------------
__global__ __launch_bounds__(128) void finalize1_k(
    const float* __restrict__ pp, const float* __restrict__ Wq_r,
    const float* __restrict__ Wq_p, const float* __restrict__ c1_r,
    const float* __restrict__ c1_p, const float* __restrict__ b_ma1,
    const float* __restrict__ g, const float* __restrict__ beta, float Nf,
    short* __restrict__ WtB, float* __restrict__ bias) {
    int k = blockIdx.x, h = threadIdx.x, kk = k & 127;
    const float* Wq = (k < 128) ? Wq_r : Wq_p;
    float ssum = 0.f, ssq = 0.f;
#pragma unroll 8
    for (int j = 0; j < 64; ++j) {
        ssum += pp[j * 256 + kk];
        ssq += pp[j * 256 + 128 + kk];
    }
    float mean = ssum / Nf;
    float var = ssq / Nf - mean * mean;
    float sv = g[kk] * rsqrtf(var + BN_EPS);
    float v = Wq[h * 128 + kk] * sv;
    int ks = k >> 5, hi = (k >> 3) & 3, j2 = k & 7;
    int ntile = h >> 4, lc = h & 15, lane = hi * 16 + lc;
    WtB[((ntile * 8 + ks) * 64 + lane) * 8 + j2] = (short)f2bf_bits(v);
    if (kk == 0) {
        __shared__ float t1[128];
        float sh = 0.f, qh = 0.f;
#pragma unroll 8
        for (int j = 0; j < 64; ++j) {
            sh += pp[j * 256 + h];
            qh += pp[j * 256 + 128 + h];
        }
        float mh = sh / Nf;
        float vh = qh / Nf - mh * mh;
        float svh = g[h] * rsqrtf(vh + BN_EPS);
        t1[h] = beta[h] - mh * svh;
        __syncthreads();
        float sb = 0.f;
#pragma unroll 4
        for (int d = 0; d < 128; ++d) sb = fmaf(Wq[h * 128 + d], t1[d], sb);
        if (k == 0) {
            bias[h] = b_ma1[h];
            bias[128 + h] = sb + c1_r[h];
        } else {
            bias[256 + h] = sb + c1_p[h];
        }
    }
}

// ---------------------------------------------------------------------------
// finalize2: from pp2 stats, emit WtBo frags (K=128) + b_out.
// ---------------------------------------------------------------------------
__global__ __launch_bounds__(128) void finalize2_k(
    const float* __restrict__ pp, const float* __restrict__ w_ma2,
    const float* __restrict__ b_ma2, const float* __restrict__ g,
    const float* __restrict__ beta, float Nf, short* __restrict__ WtBo,
    float* __restrict__ b_out) {
    int k = blockIdx.x, h = threadIdx.x;
    float ssum = 0.f, ssq = 0.f;
#pragma unroll 8
    for (int j = 0; j < 64; ++j) {
        ssum += pp[j * 256 + k];
        ssq += pp[j * 256 + 128 + k];
    }
    float mean = ssum / Nf;
    float var = ssq / Nf - mean * mean;
    float sv = g[k] * rsqrtf(var + BN_EPS);
    float v = w_ma2[h * 128 + k] * sv;
    int ks = k >> 5, hi = (k >> 3) & 3, j2 = k & 7;
    int ntile = h >> 4, lc = h & 15, lane = hi * 16 + lc;
    WtBo[((ntile * 4 + ks) * 64 + lane) * 8 + j2] = (short)f2bf_bits(v);
    if (k == 0) {
        __shared__ float t2[128];
        float sh = 0.f, qh = 0.f;
#pragma unroll 8
        for (int j = 0; j < 64; ++j) {
            sh += pp[j * 256 + h];
            qh += pp[j * 256 + 128 + h];
        }
        float mh = sh / Nf;
        float vh = qh / Nf - mh * mh;
        float svh = g[h] * rsqrtf(vh + BN_EPS);
        t2[h] = beta[h] - mh * svh;
        __syncthreads();
        float sb = 0.f;
#pragma unroll 4
        for (int d = 0; d < 128; ++d) sb = fmaf(w_ma2[h * 128 + d], t2[d], sb);
        b_out[h] = sb + b_ma2[h];
    }
}

// ---------------------------------------------------------------------------
// dense MFMA GEMM (GEMM5): Out[n,0:128] = bf16(A[n,0:128]) @ W + bias
// AT = float (in-place safe: A staged to LDS before stores) or bf16.
// ---------------------------------------------------------------------------
template <typename AT>
__global__ __launch_bounds__(512, 4) void gemm_dense_mfma(
    const AT* A, const short* __restrict__ WtB,
    const float* __restrict__ biasv, float* Out) {
    __shared__ alignas(16) short Asm[64][136];
    const int t = threadIdx.x, n0 = blockIdx.x * 64;
    const int lane = t & 63, w = t >> 6;
    const int lrow = lane & 15, lhi = lane >> 4;

    {
        int row = t >> 3, g8 = t & 7;
        u32* aw = (u32*)&Asm[0][0];
        int wb = row * 68 + g8 * 8;
        if constexpr (sizeof(AT) == 4) {
            const float* p = (const float*)A + (size_t)(n0 + row) * 128 + g8 * 16;
#pragma unroll
            for (int c = 0; c < 2; ++c) {
                float4 a = *(const float4*)(p + c * 8);
                float4 b2 = *(const float4*)(p + c * 8 + 4);
                u32 pk0 = f2bf_bits(a.x) | (f2bf_bits(a.y) << 16);
                u32 pk1 = f2bf_bits(a.z) | (f2bf_bits(a.w) << 16);
                u32 pk2 = f2bf_bits(b2.x) | (f2bf_bits(b2.y) << 16);
                u32 pk3 = f2bf_bits(b2.z) | (f2bf_bits(b2.w) << 16);
                *(uint4*)&aw[wb + c * 4] = make_uint4(pk0, pk1, pk2, pk3);
            }
        } else {
            const __hip_bfloat16* p =
                (const __hip_bfloat16*)A + (size_t)(n0 + row) * 128 + g8 * 16;
            uint4 q0 = *(const uint4*)p;
            uint4 q1 = *(const uint4*)(p + 8);
            *(uint4*)&aw[wb] = q0;
            *(uint4*)&aw[wb + 4] = q1;
        }
    }
    short8 bfrag[4];
#pragma unroll
    for (int ks = 0; ks < 4; ++ks)
        bfrag[ks] = *(const short8*)(WtB + (size_t)((w * 4 + ks) * 64 + lane) * 8);
    __syncthreads();

    f32x4 acc[4];
#pragma unroll
    for (int rt = 0; rt < 4; ++rt) acc[rt] = (f32x4){0.f, 0.f, 0.f, 0.f};
#pragma unroll
    for (int rt = 0; rt < 4; ++rt)
#pragma unroll
        for (int ks = 0; ks < 4; ++ks) {
            short8 af = *(const short8*)&Asm[rt * 16 + lrow][ks * 32 + lhi * 8];
            acc[rt] = MFMA16(af, bfrag[ks], acc[rt]);
        }
    int col = w * 16 + lrow;
    float bb = biasv[col];
#pragma unroll
    for (int rt = 0; rt < 4; ++rt)
#pragma unroll
        for (int i = 0; i < 4; ++i) {
            int row = rt * 16 + lhi * 4 + i;
            Out[(size_t)(n0 + row) * 128 + col] = acc[rt][i] + bb;
        }
}

// ---------------------------------------------------------------------------
// MFMA gather GEMM (R8 geometry, interleaved halves, optional NT output).
// node-major src [nsrc, B=8, 128] bf16. Block = 8 bins x 8 batches = 64 rows,
// 512 threads = 8 waves; wave w owns bin (blockIdx*8+w); lane: batch=lane>>3,
// ck=lane&7; one 2KB burst per edge; both halves' edge loops interleaved.
// NT: non-temporal Out stores (write stream bypasses L2/L3 -> src stays hot).
// PERM: Out row = batch*permN + bin (batch-major); else blockIdx*64+row.
// ---------------------------------------------------------------------------
template <typename OT, bool PERM, bool NT>
__global__ __launch_bounds__(512, 4) void gemm_gather_mfma(
    const __hip_bfloat16* __restrict__ src,
    const int* __restrict__ off1, const int* __restrict__ idx1,
    const int* __restrict__ off2, const int* __restrict__ idx2,
    const short* __restrict__ WtB, const float* __restrict__ biasv,
    OT* __restrict__ Out, int permN, float* __restrict__ part) {
    __shared__ alignas(16) short Asm[64][264];
    __shared__ float m1s[64], m2s[64];
    const int t = threadIdx.x;
    const int lane = t & 63;
    const int w = __builtin_amdgcn_readfirstlane(t >> 6);
    const int lrow = lane & 15, lhi = lane >> 4;
    const int bin0 = blockIdx.x * 8;

    // B fragments early (in flight during gather); wave w -> col-tile w
    short8 bfrag[8];
#pragma unroll
    for (int ks = 0; ks < 8; ++ks)
        bfrag[ks] = *(const short8*)(WtB + (size_t)((w * 8 + ks) * 64 + lane) * 8);

    // ---- gather: wave w -> bin rb; both halves interleaved ----
    {
        const int rb = bin0 + w;
        const int batch = lane >> 3, ck = lane & 7;
        const int arow = w * 8 + batch;
        const __hip_bfloat16* lsrc = src + batch * 128 + ck * 16;
        int ea = off1[rb];
        const int e1a = off1[rb + 1];
        int eb = off2[rb];
        const int e1b = off2[rb + 1];
        const int cnta = e1a - ea, cntb = e1b - eb;
        float ga[16], gb[16];
#pragma unroll
        for (int j = 0; j < 16; ++j) { ga[j] = 0.f; gb[j] = 0.f; }
        while (ea < e1a && eb < e1b) {
            int ia = idx1[ea++];
            int ib = idx2[eb++];
            acc16(lsrc + (size_t)ia * 1024, ga);
            acc16(lsrc + (size_t)ib * 1024, gb);
        }
        for (; ea + 2 <= e1a; ea += 2) {
            int i0 = idx1[ea], i1 = idx1[ea + 1];
            acc16(lsrc + (size_t)i0 * 1024, ga);
            acc16(lsrc + (size_t)i1 * 1024, ga);
        }
        if (ea < e1a) acc16(lsrc + (size_t)idx1[ea] * 1024, ga);
        for (; eb + 2 <= e1b; eb += 2) {
            int i0 = idx2[eb], i1 = idx2[eb + 1];
            acc16(lsrc + (size_t)i0 * 1024, gb);
            acc16(lsrc + (size_t)i1 * 1024, gb);
        }
        if (eb < e1b) acc16(lsrc + (size_t)idx2[eb] * 1024, gb);

        float sca = (cnta > 0) ? 1.f / (float)cnta : 0.f;
        float scb = (cntb > 0) ? 1.f / (float)cntb : 0.f;
        if (ck == 0) {
            m1s[arow] = (cnta > 0) ? 1.f : 0.f;
            m2s[arow] = (cntb > 0) ? 1.f : 0.f;
        }
        u32* aw = (u32*)&Asm[0][0];
        int wba = arow * 132 + ck * 8;
        u32 pk[8];
#pragma unroll
        for (int q = 0; q < 8; ++q)
            pk[q] = f2bf_bits(ga[q * 2] * sca) | (f2bf_bits(ga[q * 2 + 1] * sca) << 16);
        *(uint4*)&aw[wba] = make_uint4(pk[0], pk[1], pk[2], pk[3]);
        *(uint4*)&aw[wba + 4] = make_uint4(pk[4], pk[5], pk[6], pk[7]);
#pragma unroll
        for (int q = 0; q < 8; ++q)
            pk[q] = f2bf_bits(gb[q * 2] * scb) | (f2bf_bits(gb[q * 2 + 1] * scb) << 16);
        *(uint4*)&aw[wba + 64] = make_uint4(pk[0], pk[1], pk[2], pk[3]);
        *(uint4*)&aw[wba + 68] = make_uint4(pk[4], pk[5], pk[6], pk[7]);
    }
    __syncthreads();

    // ---- MFMA: 4 row-tiles x 8 k-steps; wave w -> col-tile w ----
    f32x4 acc[4];
#pragma unroll
    for (int rt = 0; rt < 4; ++rt) acc[rt] = (f32x4){0.f, 0.f, 0.f, 0.f};
#pragma unroll
    for (int rt = 0; rt < 4; ++rt)
#pragma unroll
        for (int ks = 0; ks < 8; ++ks) {
            short8 af = *(const short8*)&Asm[rt * 16 + lrow][ks * 32 + lhi * 8];
            acc[rt] = MFMA16(af, bfrag[ks], acc[rt]);
        }

    // ---- epilogue ----
    const int col = w * 16 + lrow;
    float bb = biasv[col], bm1 = biasv[128 + col], bm2 = biasv[256 + col];
    float ps = 0.f, pq = 0.f;
#pragma unroll
    for (int rt = 0; rt < 4; ++rt)
#pragma unroll
        for (int i = 0; i < 4; ++i) {
            int row = rt * 16 + lhi * 4 + i;
            float v = acc[rt][i] + bb + m1s[row] * bm1 + m2s[row] * bm2;
            v = fmaxf(v, 0.f);
            ps += v;
            pq += v * v;
            size_t orow = PERM ? ((size_t)(row & 7) * permN + (bin0 + (row >> 3)))
                               : (size_t)(blockIdx.x * 64 + row);
            if constexpr (NT)
                storent(&Out[orow * 128 + col], v);
            else
                storev(&Out[orow * 128 + col], v);
        }
    ps += __shfl_xor(ps, 16);
    ps += __shfl_xor(ps, 32);
    pq += __shfl_xor(pq, 16);
    pq += __shfl_xor(pq, 32);
    if (lhi == 0) {
        __builtin_nontemporal_store(ps, &part[(size_t)blockIdx.x * 256 + col]);
        __builtin_nontemporal_store(pq, &part[(size_t)blockIdx.x * 256 + 128 + col]);
    }
}

// ---------------------------------------------------------------------------
// launch
// ---------------------------------------------------------------------------
extern "C" void kernel_launch(void* const* d_in, const int* in_sizes, int n_in,
                              void* d_out, int out_size, void* d_ws, size_t ws_size,
                              hipStream_t stream) {
    const float* nodes = (const float*)d_in[0];
    const int* r2e = (const int*)d_in[1];
    const int* p2e = (const int*)d_in[2];
    const int* e2r = (const int*)d_in[3];
    const int* e2p = (const int*)d_in[4];
    const float* w_rct = (const float*)d_in[5];
    const float* b_rct = (const float*)d_in[6];
    const float* w_prd = (const float*)d_in[7];
    const float* b_prd = (const float*)d_in[8];
    const float* w_ra1 = (const float*)d_in[9];
    const float* b_ra1 = (const float*)d_in[10];
    const float* bn_r_g = (const float*)d_in[11];
    const float* bn_r_b = (const float*)d_in[12];
    const float* w_ra2 = (const float*)d_in[13];
    const float* b_ra2 = (const float*)d_in[14];
    const float* w_r2rct = (const float*)d_in[15];
    const float* b_r2rct = (const float*)d_in[16];
    const float* w_r2prd = (const float*)d_in[17];
    const float* b_r2prd = (const float*)d_in[18];
    const float* w_ma1 = (const float*)d_in[19];
    const float* b_ma1 = (const float*)d_in[20];
    const float* bn_m_g = (const float*)d_in[21];
    const float* bn_m_b = (const float*)d_in[22];
    const float* w_ma2 = (const float*)d_in[23];
    const float* b_ma2 = (const float*)d_in[24];

    char* ws = (char*)d_ws;
    size_t off = 0;
    auto alloc = [&](size_t bytes) -> char* {
        off = (off + 255) & ~(size_t)255;
        char* p = ws + off;
        off += bytes;
        return p;
    };

    const size_t H1B = (size_t)NR * NB * 128 * 2;  // 102.4 MB node-major [R,B,128]
    __hip_bfloat16* h1 = (__hip_bfloat16*)alloc(H1B);

    // counters block (zeroed): 4 counts + 4 cursors
    const size_t CNTI = (size_t)2 * (NR + NR + NM + NM);
    char* cntcur = alloc(CNTI * 4);
    int* cnt_r = (int*)cntcur;
    int* cnt_p = cnt_r + NR;
    int* cnt_er = cnt_p + NR;
    int* cnt_ep = cnt_er + NM;
    int* cur_r = cnt_ep + NM;
    int* cur_p = cur_r + NR;
    int* cur_er = cur_p + NR;
    int* cur_ep = cur_er + NM;

    int* off_r = (int*)alloc((NR + 1) * 4);
    int* off_p = (int*)alloc((NR + 1) * 4);
    int* off_er = (int*)alloc((NM + 1) * 4);
    int* off_ep = (int*)alloc((NM + 1) * 4);
    int* idx_r = (int*)alloc(NE * 4);
    int* idx_p = (int*)alloc(NE * 4);
    int* idx_er = (int*)alloc(NE * 4);
    int* idx_ep = (int*)alloc(NE * 4);

    float* bias1 = (float*)alloc(3 * 128 * 4);
    float* bias2 = (float*)alloc(3 * 128 * 4);
    float* b_out = (float*)alloc(128 * 4);
    float* Wq_r = (float*)alloc(128 * 128 * 4);
    float* Wq_p = (float*)alloc(128 * 128 * 4);
    float* c1_r = (float*)alloc(128 * 4);
    float* c1_p = (float*)alloc(128 * 4);
    short* WtB1 = (short*)alloc(256 * 128 * 2);
    short* WtB2 = (short*)alloc(256 * 128 * 2);
    short* WtBo = (short*)alloc(128 * 128 * 2);
    const int NBLK1 = NR / 8;  // 6250
    const int NBLK2 = NM / 8;  // 2500
    float* part1 = (float*)alloc((size_t)NBLK1 * 256 * 4);  // 6.4 MB
    float* part2 = part1;                                   // sequential reuse
    float* pp1 = (float*)alloc(64 * 256 * 4);
    float* pp2 = pp1;  // sequential reuse

    // optional bf16 h2 buffer (only used if workspace is large enough)
    __hip_bfloat16* h2bf = (__hip_bfloat16*)alloc((size_t)NB * NM * 128 * 2);
    const bool bf16h2 = (off <= ws_size);

    // nb16 [M,B,128] bf16 (41 MB) lives in d_out (dead after gather1)
    __hip_bfloat16* nb16 = (__hip_bfloat16*)d_out;

    hipMemsetAsync(cntcur, 0, CNTI * 4, stream);

    // ---- CSR build (fused) ----
    const int EB = (NE + 255) / 256;
    hist4_k<<<dim3(EB, 4), 256, 0, stream>>>(r2e, p2e, e2r, e2p,
                                             cnt_r, cnt_p, cnt_er, cnt_ep);
    scan4_k<<<4, 1024, 0, stream>>>(cnt_r, off_r, NR, cnt_p, off_p, NR,
                                    cnt_er, off_er, NM, cnt_ep, off_ep, NM);
    fill4_k<<<dim3(EB, 4), 256, 0, stream>>>(r2e, p2e, e2r, e2p,
                                             off_r, off_p, off_er, off_ep,
                                             cur_r, cur_p, cur_er, cur_ep,
                                             idx_r, idx_p, idx_er, idx_ep);

    // ---- fused admin: cast + WtB1/bias1 + Wq chain ----
    prep_all_k<<<NCAST + 384, 256, 0, stream>>>(
        nodes, nb16, w_rct, w_prd, w_ra1, b_rct, b_prd, b_ra1, WtB1, bias1,
        w_ma1, w_r2rct, w_r2prd, b_r2rct, b_r2prd, w_ra2, b_ra2,
        Wq_r, Wq_p, c1_r, c1_p);

    // ---- GEMM2 (gather): h1 = relu(gather(nb16)@Wt1 + biases) + BN1 partials ----
    // NT stores: the 102 MB h1 write stream must not evict the 41 MB nb16 src.
    gemm_gather_mfma<__hip_bfloat16, false, true><<<NBLK1, 512, 0, stream>>>(
        nb16, off_r, idx_r, off_p, idx_p, WtB1, bias1, h1, 0, part1);
    reduce_part_k<<<64, 256, 0, stream>>>(part1, NBLK1, (NBLK1 + 63) / 64, pp1);
    finalize1_k<<<256, 128, 0, stream>>>(pp1, Wq_r, Wq_p, c1_r, c1_p, b_ma1,
                                         bn_r_g, bn_r_b, (float)((size_t)NB * NR),
                                         WtB2, bias2);

    // ---- GEMM4 (gather): h2 = relu(gather(h1)@Wt2 + biases) + BN2 partials ----
    // h2 stays cached (read immediately by GEMM5).
    if (bf16h2) {
        gemm_gather_mfma<__hip_bfloat16, true, false><<<NBLK2, 512, 0, stream>>>(
            h1, off_er, idx_er, off_ep, idx_ep, WtB2, bias2, h2bf, NM, part2);
    } else {
        gemm_gather_mfma<float, true, false><<<NBLK2, 512, 0, stream>>>(
            h1, off_er, idx_er, off_ep, idx_ep, WtB2, bias2,
            (float*)d_out, NM, part2);
    }
    reduce_part_k<<<64, 256, 0, stream>>>(part2, NBLK2, (NBLK2 + 63) / 64, pp2);
    finalize2_k<<<128, 128, 0, stream>>>(pp2, w_ma2, b_ma2, bn_m_g, bn_m_b,
                                         (float)((size_t)NB * NM), WtBo, b_out);

    // ---- GEMM5 (MFMA) -> d_out ----
    if (bf16h2) {
        gemm_dense_mfma<__hip_bfloat16><<<(NB * NM) / 64, 512, 0, stream>>>(
            h2bf, WtBo, b_out, (float*)d_out);
    } else {
        gemm_dense_mfma<float><<<(NB * NM) / 64, 512, 0, stream>>>(
            (float*)d_out, WtBo, b_out, (float*)d_out);
    }
}

// Round 13
// 321.364 us; speedup vs baseline: 2.4295x; 1.2102x over previous
//
#include <hip/hip_runtime.h>
#include <hip/hip_bf16.h>

#define NB 8
#define NM 20000
#define NR 50000
#define NE 100000
#define BN_EPS 1e-5f

typedef unsigned int u32;

using short8 = __attribute__((ext_vector_type(8))) short;  // 8 bf16
using f32x4 = __attribute__((ext_vector_type(4))) float;
using fvec4 = __attribute__((ext_vector_type(4))) float;  // NT-loadable float4

#define MFMA16(a, b, c) __builtin_amdgcn_mfma_f32_16x16x32_bf16(a, b, c, 0, 0, 0)

__device__ inline u32 f2bf_bits(float f) {
    u32 x = __float_as_uint(f);
    return (x + 0x7fffu + ((x >> 16) & 1u)) >> 16;
}
__device__ inline void storev(float* p, float v) { *p = v; }
__device__ inline void storev(__hip_bfloat16* p, float v) {
    *(unsigned short*)p = (unsigned short)f2bf_bits(v);
}

// accumulate 16 bf16 cols (32B) into fp32
__device__ inline void acc16(const __hip_bfloat16* p, float* g) {
    uint4 q0 = *(const uint4*)p;
    uint4 q1 = *(const uint4*)(p + 8);
    u32 ww[8] = {q0.x, q0.y, q0.z, q0.w, q1.x, q1.y, q1.z, q1.w};
#pragma unroll
    for (int q = 0; q < 8; ++q) {
        g[q * 2] += __uint_as_float(ww[q] << 16);
        g[q * 2 + 1] += __uint_as_float(ww[q] & 0xFFFF0000u);
    }
}

// chunk-table for the wide scan: 4 lists (r, p, er, ep)
#define C_R 196  // ceil(NR/256)
#define C_M 79   // ceil(NM/256)
#define S1 196
#define S2 392
#define S3 471
#define NCHUNK 550

__device__ inline void chunk_decode(int b, int& list, int& lc) {
    if (b < S1) { list = 0; lc = b; }
    else if (b < S2) { list = 1; lc = b - S1; }
    else if (b < S3) { list = 2; lc = b - S2; }
    else { list = 3; lc = b - S3; }
}

// ---------------------------------------------------------------------------
// fill (fused 4-list)
// ---------------------------------------------------------------------------
__global__ __launch_bounds__(256) void fill4_k(
    const int* __restrict__ l0, const int* __restrict__ l1,
    const int* __restrict__ l2, const int* __restrict__ l3,
    const int* __restrict__ o0, const int* __restrict__ o1,
    const int* __restrict__ o2, const int* __restrict__ o3,
    int* u0, int* u1, int* u2, int* u3,
    int* x0, int* x1, int* x2, int* x3) {
    int i = blockIdx.x * 256 + threadIdx.x;
    if (i >= NE) return;
    const int *e, *o;
    int *cur, *idx;
    switch (blockIdx.y) {
        case 0: e = l0; o = o0; cur = u0; idx = x0; break;
        case 1: e = l1; o = o1; cur = u1; idx = x1; break;
        case 2: e = l2; o = o2; cur = u2; idx = x2; break;
        default: e = l3; o = o3; cur = u3; idx = x3; break;
    }
    int d = e[NE + i];
    int p = atomicAdd(&cur[d], 1);
    idx[o[d] + p] = e[i];
}

// ---------------------------------------------------------------------------
// wide scan phase 1: per-256-chunk sums
// ---------------------------------------------------------------------------
__global__ __launch_bounds__(256) void bsum_k(const int* __restrict__ c0,
                                              const int* __restrict__ c1,
                                              const int* __restrict__ c2,
                                              const int* __restrict__ c3,
                                              int* __restrict__ csum) {
    __shared__ int wsum[4];
    int b = blockIdx.x, t = threadIdx.x, lane = t & 63, w = t >> 6;
    int list, lc;
    chunk_decode(b, list, lc);
    const int* c = (list == 0) ? c0 : (list == 1) ? c1 : (list == 2) ? c2 : c3;
    int n = (list < 2) ? NR : NM;
    int i = lc * 256 + t;
    int x = (i < n) ? c[i] : 0;
#pragma unroll
    for (int s = 1; s < 64; s <<= 1) x += __shfl_xor(x, s);
    if (lane == 0) wsum[w] = x;
    __syncthreads();
    if (t == 0) csum[b] = wsum[0] + wsum[1] + wsum[2] + wsum[3];
}

// ---------------------------------------------------------------------------
// wide scan phase 2: 1 block; wave L scans list L's chunk sums (exclusive)
// ---------------------------------------------------------------------------
__global__ __launch_bounds__(256) void scantop_k(const int* __restrict__ csum,
                                                 int* __restrict__ gbase) {
    int t = threadIdx.x, lane = t & 63, w = t >> 6;
    const int starts[4] = {0, S1, S2, S3};
    const int counts[4] = {C_R, C_R, C_M, C_M};
    int S = starts[w], C = counts[w];
    int carry = 0;
    for (int r = 0; r * 64 < C; ++r) {
        int i = r * 64 + lane;
        int v = (i < C) ? csum[S + i] : 0;
        int x = v;
#pragma unroll
        for (int s = 1; s < 64; s <<= 1) {
            int y = __shfl_up(x, s);
            if (lane >= s) x += y;
        }
        if (i < C) gbase[S + i] = carry + x - v;  // exclusive
        carry += __shfl(x, 63);
    }
}

// ---------------------------------------------------------------------------
// wide scan phase 3: per-chunk inclusive scan + base -> off[i+1]; off[0]=0
// ---------------------------------------------------------------------------
__global__ __launch_bounds__(256) void apply_k(
    const int* __restrict__ c0, const int* __restrict__ c1,
    const int* __restrict__ c2, const int* __restrict__ c3,
    int* __restrict__ o0, int* __restrict__ o1,
    int* __restrict__ o2, int* __restrict__ o3,
    const int* __restrict__ gbase) {
    __shared__ int wsum[4];
    int b = blockIdx.x, t = threadIdx.x, lane = t & 63, w = t >> 6;
    int list, lc;
    chunk_decode(b, list, lc);
    const int* c = (list == 0) ? c0 : (list == 1) ? c1 : (list == 2) ? c2 : c3;
    int* o = (list == 0) ? o0 : (list == 1) ? o1 : (list == 2) ? o2 : o3;
    int n = (list < 2) ? NR : NM;
    int i = lc * 256 + t;
    int v = (i < n) ? c[i] : 0;
    int x = v;
#pragma unroll
    for (int s = 1; s < 64; s <<= 1) {
        int y = __shfl_up(x, s);
        if (lane >= s) x += y;
    }
    if (lane == 63) wsum[w] = x;
    __syncthreads();
    int add = 0;
#pragma unroll
    for (int j = 0; j < 3; ++j)
        if (w > j) add += wsum[j];
    if (i < n) o[i + 1] = gbase[b] + x + add;
    if (lc == 0 && t == 0) o[0] = 0;
}

// ---------------------------------------------------------------------------
// prep_all: grid-fused admin (cast | WtB1 | Wq chain | hist4)
// ---------------------------------------------------------------------------
#define NCAST 10000
#define HISTB 391  // ceil(NE/256)
__global__ __launch_bounds__(256) void prep_all_k(
    const float* __restrict__ nodes, __hip_bfloat16* __restrict__ nb16,
    const float* __restrict__ w_rct, const float* __restrict__ w_prd,
    const float* __restrict__ w_ra1, const float* __restrict__ b_rct,
    const float* __restrict__ b_prd, const float* __restrict__ b_ra1,
    short* __restrict__ WtB1, float* __restrict__ bias1,
    const float* __restrict__ w_ma1, const float* __restrict__ w_r2rct,
    const float* __restrict__ w_r2prd, const float* __restrict__ b_r2rct,
    const float* __restrict__ b_r2prd, const float* __restrict__ w_ra2,
    const float* __restrict__ b_ra2, float* __restrict__ Wq_r,
    float* __restrict__ Wq_p, float* __restrict__ c1_r, float* __restrict__ c1_p,
    const int* __restrict__ r2e, const int* __restrict__ p2e,
    const int* __restrict__ e2r, const int* __restrict__ e2p,
    int* __restrict__ cnt_r, int* __restrict__ cnt_p,
    int* __restrict__ cnt_er, int* __restrict__ cnt_ep) {
    __shared__ float smem[384];
    const int blk = blockIdx.x, t = threadIdx.x;
    if (blk < NCAST) {  // cast section (NT loads: nodes is read-once)
        int id = blk * 256 + t;
        int c8 = (id & 15) * 8;
        int b = (id >> 4) & 7;
        int m = id >> 7;
        const float* p = nodes + ((size_t)b * NM + m) * 128 + c8;
        fvec4 a = __builtin_nontemporal_load((const fvec4*)p);
        fvec4 b2 = __builtin_nontemporal_load((const fvec4*)(p + 4));
        u32 pk0 = f2bf_bits(a.x) | (f2bf_bits(a.y) << 16);
        u32 pk1 = f2bf_bits(a.z) | (f2bf_bits(a.w) << 16);
        u32 pk2 = f2bf_bits(b2.x) | (f2bf_bits(b2.y) << 16);
        u32 pk3 = f2bf_bits(b2.z) | (f2bf_bits(b2.w) << 16);
        *(uint4*)(nb16 + ((size_t)m * 8 + b) * 128 + c8) = make_uint4(pk0, pk1, pk2, pk3);
        return;
    }
    if (blk < NCAST + 128) {  // WtB1 frags
        float (*col2)[128] = (float(*)[128])smem;
        int half = t >> 7, h = t & 127;
        int k = (blk - NCAST) * 2 + half;
        const float* wsrc = (k < 128) ? w_rct : w_prd;
        int kk = k & 127;
        col2[half][h] = wsrc[h * 128 + kk];
        __syncthreads();
        float s = 0.f;
#pragma unroll 4
        for (int j = 0; j < 128; ++j) s = fmaf(w_ra1[h * 128 + j], col2[half][j], s);
        int ks = k >> 5, hi = (k >> 3) & 3, j2 = k & 7;
        int ntile = h >> 4, lc = h & 15, lane = hi * 16 + lc;
        WtB1[((ntile * 8 + ks) * 64 + lane) * 8 + j2] = (short)f2bf_bits(s);
        if (k == 0) {
            float sb1 = 0.f, sb2 = 0.f;
            for (int j = 0; j < 128; ++j) {
                float w = w_ra1[h * 128 + j];
                sb1 = fmaf(w, b_rct[j], sb1);
                sb2 = fmaf(w, b_prd[j], sb2);
            }
            bias1[h] = b_ra1[h];
            bias1[128 + h] = sb1;
            bias1[256 + h] = sb2;
        }
        return;
    }
    if (blk < NCAST + 384) {  // Wq chain section
        float* rowv = smem;
        float* Prow = smem + 128;
        float* red = smem + 256;
        int blk2 = blk - (NCAST + 128);
        bool sec = blk2 >= 128;
        int h = blk2 & 127;
        const float* wr2 = sec ? w_r2prd : w_r2rct;
        const float* br2 = sec ? b_r2prd : b_r2rct;
        float* Wq = sec ? Wq_p : Wq_r;
        float* c1 = sec ? c1_p : c1_r;
        if (t < 128) rowv[t] = w_ma1[h * 128 + t];
        __syncthreads();
        if (t < 128) {
            float s = 0.f;
#pragma unroll 4
            for (int j = 0; j < 128; ++j) s = fmaf(rowv[j], wr2[j * 128 + t], s);
            Prow[t] = s;
            red[t] = rowv[t] * br2[t];
        }
        __syncthreads();
        for (int o = 64; o > 0; o >>= 1) {
            if (t < o) red[t] += red[t + o];
            __syncthreads();
        }
        float c1a = red[0];
        __syncthreads();
        if (t < 128) {
            float s = 0.f;
#pragma unroll 4
            for (int j = 0; j < 128; ++j) s = fmaf(Prow[j], w_ra2[j * 128 + t], s);
            Wq[h * 128 + t] = s;
            red[t] = Prow[t] * b_ra2[t];
        }
        __syncthreads();
        for (int o = 64; o > 0; o >>= 1) {
            if (t < o) red[t] += red[t + o];
            __syncthreads();
        }
        if (t == 0) c1[h] = red[0] + c1a;
        return;
    }
    // hist section: blocks [NCAST+384, NCAST+384+4*HISTB)
    int hb = blk - (NCAST + 384);
    int list = hb / HISTB;
    int i = (hb - list * HISTB) * 256 + t;
    if (i >= NE) return;
    const int* e;
    int* c;
    switch (list) {
        case 0: e = r2e; c = cnt_r; break;
        case 1: e = p2e; c = cnt_p; break;
        case 2: e = e2r; c = cnt_er; break;
        default: e = e2p; c = cnt_ep; break;
    }
    atomicAdd(&c[e[NE + i]], 1);
}

// ---------------------------------------------------------------------------
// deterministic stat reduction: part[nblk][256] -> pp[64][256]
// ---------------------------------------------------------------------------
__global__ __launch_bounds__(256) void reduce_part_k(const float* __restrict__ part,
                                                     int nblk, int chunk,
                                                     float* __restrict__ pp) {
    int t = threadIdx.x, j = blockIdx.x;
    int r0 = j * chunk;
    int r1 = min(nblk, r0 + chunk);
    float s = 0.f;
    for (int r = r0; r < r1; ++r) s += part[(size_t)r * 256 + t];
    pp[j * 256 + t] = s;
}

// ---------------------------------------------------------------------------
// finalize1: from pp1 stats + precomputed Wq/c1, emit WtB2 frags + bias2.
// ---------------------------------------------------------------------------
__global__ __launch_bounds__(128) void finalize1_k(
    const float* __restrict__ pp, const float* __restrict__ Wq_r,
    const float* __restrict__ Wq_p, const float* __restrict__ c1_r,
    const float* __restrict__ c1_p, const float* __restrict__ b_ma1,
    const float* __restrict__ g, const float* __restrict__ beta, float Nf,
    short* __restrict__ WtB, float* __restrict__ bias) {
    int k = blockIdx.x, h = threadIdx.x, kk = k & 127;
    const float* Wq = (k < 128) ? Wq_r : Wq_p;
    float ssum = 0.f, ssq = 0.f;
#pragma unroll 8
    for (int j = 0; j < 64; ++j) {
        ssum += pp[j * 256 + kk];
        ssq += pp[j * 256 + 128 + kk];
    }
    float mean = ssum / Nf;
    float var = ssq / Nf - mean * mean;
    float sv = g[kk] * rsqrtf(var + BN_EPS);
    float v = Wq[h * 128 + kk] * sv;
    int ks = k >> 5, hi = (k >> 3) & 3, j2 = k & 7;
    int ntile = h >> 4, lc = h & 15, lane = hi * 16 + lc;
    WtB[((ntile * 8 + ks) * 64 + lane) * 8 + j2] = (short)f2bf_bits(v);
    if (kk == 0) {
        __shared__ float t1[128];
        float sh = 0.f, qh = 0.f;
#pragma unroll 8
        for (int j = 0; j < 64; ++j) {
            sh += pp[j * 256 + h];
            qh += pp[j * 256 + 128 + h];
        }
        float mh = sh / Nf;
        float vh = qh / Nf - mh * mh;
        float svh = g[h] * rsqrtf(vh + BN_EPS);
        t1[h] = beta[h] - mh * svh;
        __syncthreads();
        float sb = 0.f;
#pragma unroll 4
        for (int d = 0; d < 128; ++d) sb = fmaf(Wq[h * 128 + d], t1[d], sb);
        if (k == 0) {
            bias[h] = b_ma1[h];
            bias[128 + h] = sb + c1_r[h];
        } else {
            bias[256 + h] = sb + c1_p[h];
        }
    }
}

// ---------------------------------------------------------------------------
// finalize2: from pp2 stats, emit WtBo frags (K=128) + b_out.
// ---------------------------------------------------------------------------
__global__ __launch_bounds__(128) void finalize2_k(
    const float* __restrict__ pp, const float* __restrict__ w_ma2,
    const float* __restrict__ b_ma2, const float* __restrict__ g,
    const float* __restrict__ beta, float Nf, short* __restrict__ WtBo,
    float* __restrict__ b_out) {
    int k = blockIdx.x, h = threadIdx.x;
    float ssum = 0.f, ssq = 0.f;
#pragma unroll 8
    for (int j = 0; j < 64; ++j) {
        ssum += pp[j * 256 + k];
        ssq += pp[j * 256 + 128 + k];
    }
    float mean = ssum / Nf;
    float var = ssq / Nf - mean * mean;
    float sv = g[k] * rsqrtf(var + BN_EPS);
    float v = w_ma2[h * 128 + k] * sv;
    int ks = k >> 5, hi = (k >> 3) & 3, j2 = k & 7;
    int ntile = h >> 4, lc = h & 15, lane = hi * 16 + lc;
    WtBo[((ntile * 4 + ks) * 64 + lane) * 8 + j2] = (short)f2bf_bits(v);
    if (k == 0) {
        __shared__ float t2[128];
        float sh = 0.f, qh = 0.f;
#pragma unroll 8
        for (int j = 0; j < 64; ++j) {
            sh += pp[j * 256 + h];
            qh += pp[j * 256 + 128 + h];
        }
        float mh = sh / Nf;
        float vh = qh / Nf - mh * mh;
        float svh = g[h] * rsqrtf(vh + BN_EPS);
        t2[h] = beta[h] - mh * svh;
        __syncthreads();
        float sb = 0.f;
#pragma unroll 4
        for (int d = 0; d < 128; ++d) sb = fmaf(w_ma2[h * 128 + d], t2[d], sb);
        b_out[h] = sb + b_ma2[h];
    }
}

// ---------------------------------------------------------------------------
// dense MFMA GEMM (GEMM5): Out[n,0:128] = bf16(A[n,0:128]) @ W + bias
// ---------------------------------------------------------------------------
template <typename AT>
__global__ __launch_bounds__(512, 4) void gemm_dense_mfma(
    const AT* A, const short* __restrict__ WtB,
    const float* __restrict__ biasv, float* Out) {
    __shared__ alignas(16) short Asm[64][136];
    const int t = threadIdx.x, n0 = blockIdx.x * 64;
    const int lane = t & 63, w = t >> 6;
    const int lrow = lane & 15, lhi = lane >> 4;

    {
        int row = t >> 3, g8 = t & 7;
        u32* aw = (u32*)&Asm[0][0];
        int wb = row * 68 + g8 * 8;
        if constexpr (sizeof(AT) == 4) {
            const float* p = (const float*)A + (size_t)(n0 + row) * 128 + g8 * 16;
#pragma unroll
            for (int c = 0; c < 2; ++c) {
                float4 a = *(const float4*)(p + c * 8);
                float4 b2 = *(const float4*)(p + c * 8 + 4);
                u32 pk0 = f2bf_bits(a.x) | (f2bf_bits(a.y) << 16);
                u32 pk1 = f2bf_bits(a.z) | (f2bf_bits(a.w) << 16);
                u32 pk2 = f2bf_bits(b2.x) | (f2bf_bits(b2.y) << 16);
                u32 pk3 = f2bf_bits(b2.z) | (f2bf_bits(b2.w) << 16);
                *(uint4*)&aw[wb + c * 4] = make_uint4(pk0, pk1, pk2, pk3);
            }
        } else {
            const __hip_bfloat16* p =
                (const __hip_bfloat16*)A + (size_t)(n0 + row) * 128 + g8 * 16;
            uint4 q0 = *(const uint4*)p;
            uint4 q1 = *(const uint4*)(p + 8);
            *(uint4*)&aw[wb] = q0;
            *(uint4*)&aw[wb + 4] = q1;
        }
    }
    short8 bfrag[4];
#pragma unroll
    for (int ks = 0; ks < 4; ++ks)
        bfrag[ks] = *(const short8*)(WtB + (size_t)((w * 4 + ks) * 64 + lane) * 8);
    __syncthreads();

    f32x4 acc[4];
#pragma unroll
    for (int rt = 0; rt < 4; ++rt) acc[rt] = (f32x4){0.f, 0.f, 0.f, 0.f};
#pragma unroll
    for (int rt = 0; rt < 4; ++rt)
#pragma unroll
        for (int ks = 0; ks < 4; ++ks) {
            short8 af = *(const short8*)&Asm[rt * 16 + lrow][ks * 32 + lhi * 8];
            acc[rt] = MFMA16(af, bfrag[ks], acc[rt]);
        }
    int col = w * 16 + lrow;
    float bb = biasv[col];
#pragma unroll
    for (int rt = 0; rt < 4; ++rt)
#pragma unroll
        for (int i = 0; i < 4; ++i) {
            int row = rt * 16 + lhi * 4 + i;
            Out[(size_t)(n0 + row) * 128 + col] = acc[rt][i] + bb;
        }
}

// ---------------------------------------------------------------------------
// MFMA gather GEMM (R8 geometry, interleaved halves).
// node-major src [nsrc, B=8, 128] bf16. Block = 8 bins x 8 batches = 64 rows,
// 512 threads = 8 waves; wave w owns bin (blockIdx*8+w); lane: batch=lane>>3,
// ck=lane&7; one 2KB burst per edge; both halves' edge loops interleaved.
// PERM: Out row = batch*permN + bin (batch-major); else blockIdx*64+row.
// ---------------------------------------------------------------------------
template <typename OT, bool PERM>
__global__ __launch_bounds__(512, 4) void gemm_gather_mfma(
    const __hip_bfloat16* __restrict__ src,
    const int* __restrict__ off1, const int* __restrict__ idx1,
    const int* __restrict__ off2, const int* __restrict__ idx2,
    const short* __restrict__ WtB, const float* __restrict__ biasv,
    OT* __restrict__ Out, int permN, float* __restrict__ part) {
    __shared__ alignas(16) short Asm[64][264];
    __shared__ float m1s[64], m2s[64];
    const int t = threadIdx.x;
    const int lane = t & 63;
    const int w = __builtin_amdgcn_readfirstlane(t >> 6);
    const int lrow = lane & 15, lhi = lane >> 4;
    const int bin0 = blockIdx.x * 8;

    short8 bfrag[8];
#pragma unroll
    for (int ks = 0; ks < 8; ++ks)
        bfrag[ks] = *(const short8*)(WtB + (size_t)((w * 8 + ks) * 64 + lane) * 8);

    {
        const int rb = bin0 + w;
        const int batch = lane >> 3, ck = lane & 7;
        const int arow = w * 8 + batch;
        const __hip_bfloat16* lsrc = src + batch * 128 + ck * 16;
        int ea = off1[rb];
        const int e1a = off1[rb + 1];
        int eb = off2[rb];
        const int e1b = off2[rb + 1];
        const int cnta = e1a - ea, cntb = e1b - eb;
        float ga[16], gb[16];
#pragma unroll
        for (int j = 0; j < 16; ++j) { ga[j] = 0.f; gb[j] = 0.f; }
        while (ea < e1a && eb < e1b) {
            int ia = idx1[ea++];
            int ib = idx2[eb++];
            acc16(lsrc + (size_t)ia * 1024, ga);
            acc16(lsrc + (size_t)ib * 1024, gb);
        }
        for (; ea + 2 <= e1a; ea += 2) {
            int i0 = idx1[ea], i1 = idx1[ea + 1];
            acc16(lsrc + (size_t)i0 * 1024, ga);
            acc16(lsrc + (size_t)i1 * 1024, ga);
        }
        if (ea < e1a) acc16(lsrc + (size_t)idx1[ea] * 1024, ga);
        for (; eb + 2 <= e1b; eb += 2) {
            int i0 = idx2[eb], i1 = idx2[eb + 1];
            acc16(lsrc + (size_t)i0 * 1024, gb);
            acc16(lsrc + (size_t)i1 * 1024, gb);
        }
        if (eb < e1b) acc16(lsrc + (size_t)idx2[eb] * 1024, gb);

        float sca = (cnta > 0) ? 1.f / (float)cnta : 0.f;
        float scb = (cntb > 0) ? 1.f / (float)cntb : 0.f;
        if (ck == 0) {
            m1s[arow] = (cnta > 0) ? 1.f : 0.f;
            m2s[arow] = (cntb > 0) ? 1.f : 0.f;
        }
        u32* aw = (u32*)&Asm[0][0];
        int wba = arow * 132 + ck * 8;
        u32 pk[8];
#pragma unroll
        for (int q = 0; q < 8; ++q)
            pk[q] = f2bf_bits(ga[q * 2] * sca) | (f2bf_bits(ga[q * 2 + 1] * sca) << 16);
        *(uint4*)&aw[wba] = make_uint4(pk[0], pk[1], pk[2], pk[3]);
        *(uint4*)&aw[wba + 4] = make_uint4(pk[4], pk[5], pk[6], pk[7]);
#pragma unroll
        for (int q = 0; q < 8; ++q)
            pk[q] = f2bf_bits(gb[q * 2] * scb) | (f2bf_bits(gb[q * 2 + 1] * scb) << 16);
        *(uint4*)&aw[wba + 64] = make_uint4(pk[0], pk[1], pk[2], pk[3]);
        *(uint4*)&aw[wba + 68] = make_uint4(pk[4], pk[5], pk[6], pk[7]);
    }
    __syncthreads();

    f32x4 acc[4];
#pragma unroll
    for (int rt = 0; rt < 4; ++rt) acc[rt] = (f32x4){0.f, 0.f, 0.f, 0.f};
#pragma unroll
    for (int rt = 0; rt < 4; ++rt)
#pragma unroll
        for (int ks = 0; ks < 8; ++ks) {
            short8 af = *(const short8*)&Asm[rt * 16 + lrow][ks * 32 + lhi * 8];
            acc[rt] = MFMA16(af, bfrag[ks], acc[rt]);
        }

    const int col = w * 16 + lrow;
    float bb = biasv[col], bm1 = biasv[128 + col], bm2 = biasv[256 + col];
    float ps = 0.f, pq = 0.f;
#pragma unroll
    for (int rt = 0; rt < 4; ++rt)
#pragma unroll
        for (int i = 0; i < 4; ++i) {
            int row = rt * 16 + lhi * 4 + i;
            float v = acc[rt][i] + bb + m1s[row] * bm1 + m2s[row] * bm2;
            v = fmaxf(v, 0.f);
            ps += v;
            pq += v * v;
            size_t orow = PERM ? ((size_t)(row & 7) * permN + (bin0 + (row >> 3)))
                               : (size_t)(blockIdx.x * 64 + row);
            storev(&Out[orow * 128 + col], v);
        }
    ps += __shfl_xor(ps, 16);
    ps += __shfl_xor(ps, 32);
    pq += __shfl_xor(pq, 16);
    pq += __shfl_xor(pq, 32);
    if (lhi == 0) {
        part[(size_t)blockIdx.x * 256 + col] = ps;
        part[(size_t)blockIdx.x * 256 + 128 + col] = pq;
    }
}

// ---------------------------------------------------------------------------
// launch
// ---------------------------------------------------------------------------
extern "C" void kernel_launch(void* const* d_in, const int* in_sizes, int n_in,
                              void* d_out, int out_size, void* d_ws, size_t ws_size,
                              hipStream_t stream) {
    const float* nodes = (const float*)d_in[0];
    const int* r2e = (const int*)d_in[1];
    const int* p2e = (const int*)d_in[2];
    const int* e2r = (const int*)d_in[3];
    const int* e2p = (const int*)d_in[4];
    const float* w_rct = (const float*)d_in[5];
    const float* b_rct = (const float*)d_in[6];
    const float* w_prd = (const float*)d_in[7];
    const float* b_prd = (const float*)d_in[8];
    const float* w_ra1 = (const float*)d_in[9];
    const float* b_ra1 = (const float*)d_in[10];
    const float* bn_r_g = (const float*)d_in[11];
    const float* bn_r_b = (const float*)d_in[12];
    const float* w_ra2 = (const float*)d_in[13];
    const float* b_ra2 = (const float*)d_in[14];
    const float* w_r2rct = (const float*)d_in[15];
    const float* b_r2rct = (const float*)d_in[16];
    const float* w_r2prd = (const float*)d_in[17];
    const float* b_r2prd = (const float*)d_in[18];
    const float* w_ma1 = (const float*)d_in[19];
    const float* b_ma1 = (const float*)d_in[20];
    const float* bn_m_g = (const float*)d_in[21];
    const float* bn_m_b = (const float*)d_in[22];
    const float* w_ma2 = (const float*)d_in[23];
    const float* b_ma2 = (const float*)d_in[24];

    char* ws = (char*)d_ws;
    size_t off = 0;
    auto alloc = [&](size_t bytes) -> char* {
        off = (off + 255) & ~(size_t)255;
        char* p = ws + off;
        off += bytes;
        return p;
    };

    const size_t H1B = (size_t)NR * NB * 128 * 2;  // 102.4 MB node-major [R,B,128]
    __hip_bfloat16* h1 = (__hip_bfloat16*)alloc(H1B);

    // counters block (zeroed): 4 counts + 4 cursors
    const size_t CNTI = (size_t)2 * (NR + NR + NM + NM);
    char* cntcur = alloc(CNTI * 4);
    int* cnt_r = (int*)cntcur;
    int* cnt_p = cnt_r + NR;
    int* cnt_er = cnt_p + NR;
    int* cnt_ep = cnt_er + NM;
    int* cur_r = cnt_ep + NM;
    int* cur_p = cur_r + NR;
    int* cur_er = cur_p + NR;
    int* cur_ep = cur_er + NM;

    int* off_r = (int*)alloc((NR + 1) * 4);
    int* off_p = (int*)alloc((NR + 1) * 4);
    int* off_er = (int*)alloc((NM + 1) * 4);
    int* off_ep = (int*)alloc((NM + 1) * 4);
    int* idx_r = (int*)alloc(NE * 4);
    int* idx_p = (int*)alloc(NE * 4);
    int* idx_er = (int*)alloc(NE * 4);
    int* idx_ep = (int*)alloc(NE * 4);
    int* csum = (int*)alloc(NCHUNK * 4);
    int* gbase = (int*)alloc(NCHUNK * 4);

    float* bias1 = (float*)alloc(3 * 128 * 4);
    float* bias2 = (float*)alloc(3 * 128 * 4);
    float* b_out = (float*)alloc(128 * 4);
    float* Wq_r = (float*)alloc(128 * 128 * 4);
    float* Wq_p = (float*)alloc(128 * 128 * 4);
    float* c1_r = (float*)alloc(128 * 4);
    float* c1_p = (float*)alloc(128 * 4);
    short* WtB1 = (short*)alloc(256 * 128 * 2);
    short* WtB2 = (short*)alloc(256 * 128 * 2);
    short* WtBo = (short*)alloc(128 * 128 * 2);
    const int NBLK1 = NR / 8;  // 6250
    const int NBLK2 = NM / 8;  // 2500
    float* part1 = (float*)alloc((size_t)NBLK1 * 256 * 4);  // 6.4 MB
    float* part2 = part1;                                   // sequential reuse
    float* pp1 = (float*)alloc(64 * 256 * 4);
    float* pp2 = pp1;  // sequential reuse

    // optional bf16 h2 buffer (only used if workspace is large enough)
    __hip_bfloat16* h2bf = (__hip_bfloat16*)alloc((size_t)NB * NM * 128 * 2);
    const bool bf16h2 = (off <= ws_size);

    // nb16 [M,B,128] bf16 (41 MB) lives in d_out (dead after gather1)
    __hip_bfloat16* nb16 = (__hip_bfloat16*)d_out;

    hipMemsetAsync(cntcur, 0, CNTI * 4, stream);

    // ---- fused admin: cast + WtB1/bias1 + Wq chain + histograms ----
    prep_all_k<<<NCAST + 384 + 4 * HISTB, 256, 0, stream>>>(
        nodes, nb16, w_rct, w_prd, w_ra1, b_rct, b_prd, b_ra1, WtB1, bias1,
        w_ma1, w_r2rct, w_r2prd, b_r2rct, b_r2prd, w_ra2, b_ra2,
        Wq_r, Wq_p, c1_r, c1_p,
        r2e, p2e, e2r, e2p, cnt_r, cnt_p, cnt_er, cnt_ep);

    // ---- wide 3-phase scan -> off arrays ----
    bsum_k<<<NCHUNK, 256, 0, stream>>>(cnt_r, cnt_p, cnt_er, cnt_ep, csum);
    scantop_k<<<1, 256, 0, stream>>>(csum, gbase);
    apply_k<<<NCHUNK, 256, 0, stream>>>(cnt_r, cnt_p, cnt_er, cnt_ep,
                                        off_r, off_p, off_er, off_ep, gbase);

    // ---- fill ----
    const int EB = (NE + 255) / 256;
    fill4_k<<<dim3(EB, 4), 256, 0, stream>>>(r2e, p2e, e2r, e2p,
                                             off_r, off_p, off_er, off_ep,
                                             cur_r, cur_p, cur_er, cur_ep,
                                             idx_r, idx_p, idx_er, idx_ep);

    // ---- GEMM2 (gather): h1 = relu(gather(nb16)@Wt1 + biases) + BN1 partials ----
    gemm_gather_mfma<__hip_bfloat16, false><<<NBLK1, 512, 0, stream>>>(
        nb16, off_r, idx_r, off_p, idx_p, WtB1, bias1, h1, 0, part1);
    reduce_part_k<<<64, 256, 0, stream>>>(part1, NBLK1, (NBLK1 + 63) / 64, pp1);
    finalize1_k<<<256, 128, 0, stream>>>(pp1, Wq_r, Wq_p, c1_r, c1_p, b_ma1,
                                         bn_r_g, bn_r_b, (float)((size_t)NB * NR),
                                         WtB2, bias2);

    // ---- GEMM4 (gather): h2 = relu(gather(h1)@Wt2 + biases) + BN2 partials ----
    if (bf16h2) {
        gemm_gather_mfma<__hip_bfloat16, true><<<NBLK2, 512, 0, stream>>>(
            h1, off_er, idx_er, off_ep, idx_ep, WtB2, bias2, h2bf, NM, part2);
    } else {
        gemm_gather_mfma<float, true><<<NBLK2, 512, 0, stream>>>(
            h1, off_er, idx_er, off_ep, idx_ep, WtB2, bias2,
            (float*)d_out, NM, part2);
    }
    reduce_part_k<<<64, 256, 0, stream>>>(part2, NBLK2, (NBLK2 + 63) / 64, pp2);
    finalize2_k<<<128, 128, 0, stream>>>(pp2, w_ma2, b_ma2, bn_m_g, bn_m_b,
                                         (float)((size_t)NB * NM), WtBo, b_out);

    // ---- GEMM5 (MFMA) -> d_out ----
    if (bf16h2) {
        gemm_dense_mfma<__hip_bfloat16><<<(NB * NM) / 64, 512, 0, stream>>>(
            h2bf, WtBo, b_out, (float*)d_out);
    } else {
        gemm_dense_mfma<float><<<(NB * NM) / 64, 512, 0, stream>>>(
            (float*)d_out, WtBo, b_out, (float*)d_out);
    }
}